// Round 3
// baseline (2714.209 us; speedup 1.0000x reference)
//
#include <hip/hip_runtime.h>
#include <math.h>

// BiLSTM-CRF, round 14: barrier-free per-wave LSTM islands.
// - in-lane cell (r13 layout, verified) => each wave fully independent; the
//   S_-step loop contains NO __syncthreads. Per wave: sentinel-spin on the
//   island slab (8 coalesced u64 loads/lane), unpack to a PRIVATE 4KB LDS
//   slab, MFMA, in-lane cell, agent-store. Waves drift and overlap.
// - unit-major xg now produced by permuting Wih ROWS + bias at build time
//   (bgemm epilogue back to round-12 coalesced form).
// - hout stores re-packed to u32 via 4 __shfl (kills r13's write amplification).
// - XCD co-location: blockIdx = us*32 + island (all 8 island slices land on
//   one XCD under round-robin; perf heuristic only, never correctness).
// B=64 S=256 V=50000 E=300 H=256 T=13
#define B_    64
#define S_    256
#define E_    300
#define H_    256
#define T_    13
#define G4_   1024   // 4*H
#define D2H_  512    // 2*H

typedef short bf16x8 __attribute__((ext_vector_type(8)));   // 8 bf16 in 4 VGPRs
typedef float f32x4  __attribute__((ext_vector_type(4)));
typedef unsigned short u16;
typedef unsigned int   u32;
typedef unsigned long long u64;

#define SENT32 0x7F7F7F7Fu    // memset(0x7F) pattern; impossible packed-h dword

__device__ __forceinline__ float sigf(float x)   { return __builtin_amdgcn_rcpf(1.f + __expf(-x)); }
__device__ __forceinline__ float tanhf_(float x) { return __builtin_amdgcn_rcpf(1.f + __expf(-2.f*x))*2.f - 1.f; }

__device__ __forceinline__ u16 f2bf(float f) {
  union { float f; unsigned u; } v; v.f = f;
  unsigned r = v.u + 0x7fff + ((v.u >> 16) & 1);   // RNE
  return (u16)(r >> 16);
}
__device__ __forceinline__ float bf2f(u16 h) {
  union { unsigned u; float f; } v; v.u = ((unsigned)h) << 16;
  return v.f;
}

// coherent (agent-scope, relaxed) accessors
__device__ __forceinline__ u64 cload64(const u64* p) {
  return __hip_atomic_load(p, __ATOMIC_RELAXED, __HIP_MEMORY_SCOPE_AGENT);
}
__device__ __forceinline__ void cstore32(u32* p, u32 v) {
  __hip_atomic_store(p, v, __ATOMIC_RELAXED, __HIP_MEMORY_SCOPE_AGENT);
}

// ---------------- embedding gather -> bf16 hi/lo, K padded 300->320 ----------------
__global__ __launch_bounds__(64)
void k_embed(const int* __restrict__ x, const float* __restrict__ emb,
             u16* __restrict__ oh, u16* __restrict__ ol) {
  int bs = blockIdx.x;
  int xv = x[bs];
  const float4* src = (const float4*)(emb + (size_t)xv * E_);
  u64* dh = (u64*)(oh + (size_t)bs * 320);
  u64* dl = (u64*)(ol + (size_t)bs * 320);
  for (int q = threadIdx.x; q < 80; q += 64) {
    float4 v = (q < 75) ? src[q] : make_float4(0.f, 0.f, 0.f, 0.f);
    u16 hh[4], ll[4];
    float vv[4] = {v.x, v.y, v.z, v.w};
    #pragma unroll
    for (int j = 0; j < 4; j++) {
      hh[j] = f2bf(vv[j]);
      ll[j] = f2bf(vv[j] - bf2f(hh[j]));
    }
    dh[q] = (u64)hh[0] | ((u64)hh[1] << 16) | ((u64)hh[2] << 32) | ((u64)hh[3] << 48);
    dl[q] = (u64)ll[0] | ((u64)ll[1] << 16) | ((u64)ll[2] << 32) | ((u64)ll[3] << 48);
  }
}

// ---------------- fp32 -> bf16 hi/lo split (flat) ----------------
__global__ __launch_bounds__(256)
void k_cvtbf2(const float* __restrict__ w, u16* __restrict__ hi, u16* __restrict__ lo, int n) {
  int i = blockIdx.x * 256 + threadIdx.x;
  if (i < n) {
    float v = w[i];
    u16 h = f2bf(v);
    hi[i] = h;
    lo[i] = f2bf(v - bf2f(h));
  }
}

// ---------------- fp32 -> bf16 hi/lo, K padding, optional row permute -------------
// perm=1: source row (d, gate*256+unit) lands at buffer row (d, unit*4+gate),
// so the GEMM's output columns come out unit-major with a COALESCED epilogue.
__global__ __launch_bounds__(256)
void k_cvtpad(const float* __restrict__ w, u16* __restrict__ hi, u16* __restrict__ lo,
              int Ksrc, int Kpad, int perm) {
  int r = blockIdx.x;
  int rl = r & 1023, dd = r >> 10;
  int ro = perm ? ((dd << 10) | ((rl & 255) << 2) | (rl >> 8)) : r;
  for (int k = threadIdx.x; k < Kpad; k += 256) {
    float v = (k < Ksrc) ? w[(size_t)r * Ksrc + k] : 0.f;
    u16 h = f2bf(v);
    hi[(size_t)ro * Kpad + k] = h;
    lo[(size_t)ro * Kpad + k] = f2bf(v - bf2f(h));
  }
}

// ---------------- bias permute: (d, gate*256+unit) -> (d, unit*4+gate) ------------
__global__ __launch_bounds__(256)
void k_permb(const float* __restrict__ b, float* __restrict__ bp) {
  int i = blockIdx.x * 256 + threadIdx.x;      // 0..2047
  int rl = i & 1023, dd = i >> 10;
  bp[(dd << 10) | ((rl & 255) << 2) | (rl >> 8)] = b[i];
}

// ---------------- cond_w (512,256) -> transposed hi/lo (256,512) ----------------
__global__ __launch_bounds__(256)
void k_cvtT(const float* __restrict__ w, u16* __restrict__ hi, u16* __restrict__ lo) {
  int n = blockIdx.x;
  for (int k = threadIdx.x; k < 512; k += 256) {
    float v = w[(size_t)k * 256 + n];
    u16 h = f2bf(v);
    hi[(size_t)n * 512 + k] = h;
    lo[(size_t)n * 512 + k] = f2bf(v - bf2f(h));
  }
}

// ---------------- split-bf16 MFMA GEMM: C = A @ W^T + bias (round-12 form) --------
__global__ __launch_bounds__(256)
void k_bgemm(const u16* __restrict__ Ahi, const u16* __restrict__ Alo,
             const u16* __restrict__ Whi, const u16* __restrict__ Wlo,
             const float* __restrict__ bias, float* __restrict__ C,
             int K, int N, int permute, long wStride, long bStride, long cStride)
{
  __shared__ u16 Ash[2][128 * 40];
  __shared__ u16 Wsh[2][128 * 40];

  int tid = threadIdx.x;
  int d   = blockIdx.z;
  int n0  = blockIdx.x * 128, m0 = blockIdx.y * 128;
  int lane = tid & 63;
  int w    = tid >> 6;
  int l15  = lane & 15;
  int quad = lane >> 4;
  int mh = (w >> 1) * 64, nh = (w & 1) * 64;

  int comp = tid >> 7, row = tid & 127;
  int gr = m0 + row;
  int ar = permute ? ((gr & 63) * S_ + (gr >> 6)) : gr;
  const u16* Asrc = (comp ? Alo : Ahi) + (size_t)ar * K;
  const u16* Wsrc = (comp ? Wlo : Whi) + (size_t)d * wStride + (size_t)(n0 + row) * K;
  u16* AshC = &Ash[comp][row * 40];
  u16* WshC = &Wsh[comp][row * 40];

  f32x4 acc[4][4];
  #pragma unroll
  for (int mt = 0; mt < 4; mt++)
    #pragma unroll
    for (int nt = 0; nt < 4; nt++) acc[mt][nt] = (f32x4)(0.f);

  for (int k0 = 0; k0 < K; k0 += 32) {
    float4 a0 = *(const float4*)(Asrc + k0);
    float4 a1 = *(const float4*)(Asrc + k0 + 8);
    float4 a2 = *(const float4*)(Asrc + k0 + 16);
    float4 a3 = *(const float4*)(Asrc + k0 + 24);
    float4 w0 = *(const float4*)(Wsrc + k0);
    float4 w1 = *(const float4*)(Wsrc + k0 + 8);
    float4 w2 = *(const float4*)(Wsrc + k0 + 16);
    float4 w3 = *(const float4*)(Wsrc + k0 + 24);
    __syncthreads();
    *(float4*)(AshC)      = a0; *(float4*)(AshC + 8)  = a1;
    *(float4*)(AshC + 16) = a2; *(float4*)(AshC + 24) = a3;
    *(float4*)(WshC)      = w0; *(float4*)(WshC + 8)  = w1;
    *(float4*)(WshC + 16) = w2; *(float4*)(WshC + 24) = w3;
    __syncthreads();

    bf16x8 ah[4], al[4], bh[4], bl[4];
    #pragma unroll
    for (int mt = 0; mt < 4; mt++) {
      int rr = mh + mt * 16 + l15;
      ah[mt] = *(const bf16x8*)&Ash[0][rr * 40 + quad * 8];
      al[mt] = *(const bf16x8*)&Ash[1][rr * 40 + quad * 8];
    }
    #pragma unroll
    for (int nt = 0; nt < 4; nt++) {
      int rr = nh + nt * 16 + l15;
      bh[nt] = *(const bf16x8*)&Wsh[0][rr * 40 + quad * 8];
      bl[nt] = *(const bf16x8*)&Wsh[1][rr * 40 + quad * 8];
    }
    #pragma unroll
    for (int mt = 0; mt < 4; mt++)
      #pragma unroll
      for (int nt = 0; nt < 4; nt++) {
        acc[mt][nt] = __builtin_amdgcn_mfma_f32_16x16x32_bf16(ah[mt], bh[nt], acc[mt][nt], 0, 0, 0);
        acc[mt][nt] = __builtin_amdgcn_mfma_f32_16x16x32_bf16(ah[mt], bl[nt], acc[mt][nt], 0, 0, 0);
        acc[mt][nt] = __builtin_amdgcn_mfma_f32_16x16x32_bf16(al[mt], bh[nt], acc[mt][nt], 0, 0, 0);
      }
  }

  const float* biasd = bias + (size_t)d * bStride;
  float* Cd = C + (size_t)d * cStride;
  #pragma unroll
  for (int nt = 0; nt < 4; nt++) {
    int cn = n0 + nh + nt * 16 + l15;
    float bv = biasd[cn];
    #pragma unroll
    for (int mt = 0; mt < 4; mt++) {
      int mr = m0 + mh + mt * 16 + quad * 4;
      #pragma unroll
      for (int j = 0; j < 4; j++)
        Cd[(size_t)(mr + j) * N + cn] = acc[mt][nt][j] + bv;
    }
  }
}

// ---------------- barrier-free split-bf16 MFMA LSTM ----------------
// 256 WGs: blockIdx.x = us*32 + isl, isl = d*16 + bg (8 island slices per XCD).
// Wave w handles units us*32 + w*8 + {quad, quad+4}, all 4 gates in-lane.
// Exchange slab per (island, step): u32[bc 0..3][unit 0..255] = hh | hl<<16.
// Each wave independently spins on the full 4KB slab (coalesced u64 loads),
// unpacks into its PRIVATE LDS slab, runs MFMA + cell. No __syncthreads.
__global__ __launch_bounds__(256, 1)
void k_lstm_mfma(const float* __restrict__ xg,
                 const u16* __restrict__ Whi, const u16* __restrict__ Wlo,
                 u16* __restrict__ houth, u16* __restrict__ houtl,
                 u32* __restrict__ hbx)
{
  __shared__ __align__(16) u16 hsh[4][1024];   // per-wave hi slabs (2KB each)
  __shared__ __align__(16) u16 hsl[4][1024];   // per-wave lo slabs

  int tid  = threadIdx.x;
  int us   = blockIdx.x >> 5;
  int isl  = blockIdx.x & 31;
  int d    = isl >> 4;
  int bg   = isl & 15;
  int lane = tid & 63;
  int w    = tid >> 6;
  int l15  = lane & 15;
  int quad = lane >> 4;
  int bpc  = l15 & 3;

  // A-frags: row = gate*256 + unit, gate = l15&3, unit = us*32 + w*8 + mt*4 + (l15>>2)
  bf16x8 afh[2][8], afl[2][8];
  {
    size_t rowb = ((size_t)d * G4_ + (size_t)(l15 & 3) * 256
                   + us * 32 + w * 8 + (l15 >> 2)) * H_;
    const u16* WbH = Whi + rowb;
    const u16* WbL = Wlo + rowb;
    #pragma unroll
    for (int mt = 0; mt < 2; mt++)
      #pragma unroll
      for (int kt = 0; kt < 8; kt++) {
        afh[mt][kt] = *(const bf16x8*)(WbH + (size_t)mt * 4 * H_ + kt * 32 + quad * 8);
        afl[mt][kt] = *(const bf16x8*)(WbL + (size_t)mt * 4 * H_ + kt * 32 + quad * 8);
      }
  }
  // pin fragments in VGPRs (discourage per-step rematerialization)
  #pragma unroll
  for (int mt = 0; mt < 2; mt++)
    #pragma unroll
    for (int kt = 0; kt < 8; kt++) {
      asm volatile("" : "+v"(afh[mt][kt]));
      asm volatile("" : "+v"(afl[mt][kt]));
    }

  char* mysh = (char*)hsh[w];
  char* mysl = (char*)hsl[w];

  float c0 = 0.f, c1 = 0.f;
  u32 pk0 = 0, pk1 = 0;

  const float* xgd = xg + (size_t)d * S_ * B_ * G4_;
  u32* hb = hbx + (size_t)isl * S_ * 1024;

  for (int it = 0; it < S_; it++) {
    int s = d ? (S_ - 1 - it) : it;

    // acc init from unit-major xg (issued early; hides under the spin)
    f32x4 accA[2], accB[2];
    const float* xgrow = xgd + ((size_t)s * B_ + (bg * 4 + bpc)) * G4_
                       + (size_t)(us * 32 + w * 8 + quad) * 4;
    accA[0] = *(const f32x4*)(xgrow);
    accA[1] = *(const f32x4*)(xgrow + 16);
    accB[0] = (f32x4)(0.f);
    accB[1] = (f32x4)(0.f);

    if (it > 0) {
      const u64* src = (const u64*)(hb + (size_t)(it - 1) * 1024);
      u64 v[8];
      #pragma unroll
      for (int r = 0; r < 8; r++) v[r] = cload64(src + lane + 64 * r);
      for (;;) {
        int bad = 0;
        #pragma unroll
        for (int r = 0; r < 8; r++)
          if (((u32)v[r] == SENT32) | ((u32)(v[r] >> 32) == SENT32)) bad = 1;
        if (!__any(bad)) break;
        #pragma unroll
        for (int r = 0; r < 8; r++)
          if (((u32)v[r] == SENT32) | ((u32)(v[r] >> 32) == SENT32))
            v[r] = cload64(src + lane + 64 * r);
      }
      // unpack to private slab; u64 j covers units 2j, 2j+1 (same batch)
      #pragma unroll
      for (int r = 0; r < 8; r++) {
        int j = lane + 64 * r;
        u64 vv = v[r];
        u32 h32 = ((u32)vv & 0xFFFFu) | (((u32)(vv >> 32) & 0xFFFFu) << 16);
        u32 l32 = (((u32)(vv >> 16)) & 0xFFFFu) | (((u32)(vv >> 48)) << 16);
        int off = (4 * j) ^ (((j >> 7) & 1) << 6);
        *(u32*)(mysh + off) = h32;
        *(u32*)(mysl + off) = l32;
      }

      #pragma unroll
      for (int kt = 0; kt < 8; kt++) {
        int coff = (bpc * 512 + (kt * 4 + quad) * 16) ^ ((bpc & 1) << 6);
        bf16x8 bh = *(const bf16x8*)(mysh + coff);
        bf16x8 bl = *(const bf16x8*)(mysl + coff);
        #pragma unroll
        for (int mt = 0; mt < 2; mt++) {
          accA[mt] = __builtin_amdgcn_mfma_f32_16x16x32_bf16(afh[mt][kt], bh, accA[mt], 0, 0, 0);
          accB[mt] = __builtin_amdgcn_mfma_f32_16x16x32_bf16(afh[mt][kt], bl, accB[mt], 0, 0, 0);
          accB[mt] = __builtin_amdgcn_mfma_f32_16x16x32_bf16(afl[mt][kt], bh, accB[mt], 0, 0, 0);
        }
      }
    }

    // in-lane cell: acc[mt][j] = gate j (i,f,g,o) of unit us*32+w*8+quad + mt*4
    u32* hbrow = hb + (size_t)it * 1024 + bpc * 256 + us * 32 + w * 8 + quad;
    {
      f32x4 g0 = accA[0] + accB[0];
      c0 = sigf(g0[1]) * c0 + sigf(g0[0]) * tanhf_(g0[2]);
      float h0 = sigf(g0[3]) * tanhf_(c0);
      u16 hh = f2bf(h0), hl = f2bf(h0 - bf2f(hh));
      pk0 = (u32)hh | ((u32)hl << 16);
      if (l15 < 4) cstore32(hbrow, pk0);           // publish ASAP
    }
    {
      f32x4 g1 = accA[1] + accB[1];
      c1 = sigf(g1[1]) * c1 + sigf(g1[0]) * tanhf_(g1[2]);
      float h1 = sigf(g1[3]) * tanhf_(c1);
      u16 hh = f2bf(h1), hl = f2bf(h1 - bf2f(hh));
      pk1 = (u32)hh | ((u32)hl << 16);
      if (l15 < 4) cstore32(hbrow + 4, pk1);
    }

    // layer output: shfl-pack to u32 pairs (consecutive units) for clean stores
    {
      int srcA = ((quad & 1) << 5) + bpc;          // owner of unit 2*quad
      u32 a0 = __shfl(pk0, srcA), a1 = __shfl(pk1, srcA);
      u32 b0s = __shfl(pk0, srcA + 16), b1s = __shfl(pk1, srcA + 16);
      u32 vA = (quad >> 1) ? a1 : a0;
      u32 vB = (quad >> 1) ? b1s : b0s;
      u32 hi32 = (vA & 0xFFFFu) | ((vB & 0xFFFFu) << 16);
      u32 lo32 = (vA >> 16) | (vB & 0xFFFF0000u);
      if (l15 < 4) {
        size_t ho = ((size_t)(bg * 4 + bpc) * S_ + s) * D2H_ + d * H_
                  + us * 32 + w * 8 + quad * 2;
        *(u32*)(houth + ho) = hi32;
        *(u32*)(houtl + ho) = lo32;
      }
    }
  }
}

// ---------------- block reduction helpers ----------------
__device__ __forceinline__ float bsum(float v, float* sb) {
  int t = threadIdx.x;
  sb[t] = v; __syncthreads();
  for (int s = 128; s; s >>= 1) { if (t < s) sb[t] += sb[t + s]; __syncthreads(); }
  float r = sb[0]; __syncthreads(); return r;
}
__device__ __forceinline__ float bmax(float v, float* sb) {
  int t = threadIdx.x;
  sb[t] = v; __syncthreads();
  for (int s = 128; s; s >>= 1) { if (t < s) sb[t] = fmaxf(sb[t], sb[t + s]); __syncthreads(); }
  float r = sb[0]; __syncthreads(); return r;
}

// ---------------- pos branch ----------------
__global__ __launch_bounds__(256)
void k_pos(const float* __restrict__ pos, const float* __restrict__ fc1w, const float* __restrict__ fc1b,
           const float* __restrict__ fc2w, const float* __restrict__ fc2b,
           const float* __restrict__ lng, const float* __restrict__ lnb, float* __restrict__ pos_out)
{
  __shared__ float sp[256], sh[256], sb[256];
  int b = blockIdx.x, t = threadIdx.x;
  sp[t] = pos[b * 256 + t];
  __syncthreads();
  float a1 = fc1b[t];
  for (int s = 0; s < 256; s++) a1 += sp[s] * fc1w[s * 256 + t];
  a1 = fmaxf(a1, 0.f);
  sh[t] = a1; __syncthreads();
  float a2 = fc2b[t] + sp[t];
  for (int s = 0; s < 256; s++) a2 += sh[s] * fc2w[s * 256 + t];
  float m   = bsum(a2, sb) * (1.f / 256.f);
  float cen = a2 - m;
  float var = bsum(cen * cen, sb) * (1.f / 256.f);
  pos_out[b * 256 + t] = cen * rsqrtf(var + 1e-5f) * lng[t] + lnb[t];
}

// ---------------- CLN stage A ----------------
__global__ __launch_bounds__(256)
void k_clnA(const float* __restrict__ pos_out, const float* __restrict__ wd, const float* __restrict__ bd,
            const float* __restrict__ cw, const float* __restrict__ cb,
            float* __restrict__ wvec, float* __restrict__ bbvec)
{
  __shared__ float sp[256];
  int b = blockIdx.x, t = threadIdx.x;
  sp[t] = pos_out[b * 256 + t];
  __syncthreads();
  const float4* wdr = (const float4*)(wd + (size_t)t * 256);
  const float4* bdr = (const float4*)(bd + (size_t)t * 256);
  float aw = 0.f, ab = 0.f;
  for (int q = 0; q < 64; q++) {
    float4 w4 = wdr[q], b4 = bdr[q];
    float s0 = sp[q*4], s1 = sp[q*4+1], s2 = sp[q*4+2], s3 = sp[q*4+3];
    aw += s0*w4.x + s1*w4.y + s2*w4.z + s3*w4.w;
    ab += s0*b4.x + s1*b4.y + s2*b4.z + s3*b4.w;
  }
  wvec [b * 256 + t] = aw + cw[t];
  bbvec[b * 256 + t] = ab + cb[t];
}

// ---------------- CLN stage B + sentence dot ----------------
__global__ __launch_bounds__(256)
void k_clnB(const float* __restrict__ oc, const float* __restrict__ wvec, const float* __restrict__ bbvec,
            const float* __restrict__ alw, const float* __restrict__ alb,
            float* __restrict__ outn, float* __restrict__ sentence)
{
  __shared__ float sb[256];
  int bs = blockIdx.x, t = threadIdx.x;
  int b = bs >> 8;
  float v   = oc[(size_t)bs * 256 + t];
  float m   = bsum(v, sb) * (1.f / 256.f);
  float cen = v - m;
  float var = bsum(cen * cen, sb) * (1.f / 256.f);
  float o   = cen * rsqrtf(var + 1e-12f) * wvec[b * 256 + t] + bbvec[b * 256 + t];
  outn[(size_t)bs * 256 + t] = o;
  float sv = bsum(o * alw[t], sb);
  if (t == 0) sentence[bs] = sv + alb[0];
}

// ---------------- attention ----------------
__global__ __launch_bounds__(256)
void k_att(const float* __restrict__ sentence,
           const float* __restrict__ wq, const float* __restrict__ bq,
           const float* __restrict__ wk, const float* __restrict__ bk,
           const float* __restrict__ wv, const float* __restrict__ bv,
           const float* __restrict__ lng, const float* __restrict__ lnb,
           float* __restrict__ att)
{
  __shared__ float ss[256], sb[256];
  int b = blockIdx.x, t = threadIdx.x;
  ss[t] = sentence[b * 256 + t];
  __syncthreads();
  float q = bq[t], k = bk[t], vv = bv[t];
  for (int s = 0; s < 256; s++) {
    float sv = ss[s];
    q  += sv * wq[s * 256 + t];
    k  += sv * wk[s * 256 + t];
    vv += sv * wv[s * 256 + t];
  }
  float x  = q * k * (1.f / 16.f);
  float mx = bmax(x, sb);
  float e  = expf(x - mx);
  float sm = bsum(e, sb);
  float a  = (e / sm) * vv;
  float m   = bsum(a, sb) * (1.f / 256.f);
  float cen = a - m;
  float var = bsum(cen * cen, sb) * (1.f / 256.f);
  att[b * 256 + t] = cen * rsqrtf(var + 1e-5f) * lng[t] + lnb[t];
}

// ---------------- logits ----------------
__global__ __launch_bounds__(64)
void k_out(const float* __restrict__ outn, const float* __restrict__ att,
           const float* __restrict__ ow, const float* __restrict__ ob,
           float* __restrict__ logits)
{
  __shared__ float row[256];
  int bs = blockIdx.x, t = threadIdx.x;
  ((float4*)row)[t] = ((const float4*)(outn + (size_t)bs * 256))[t];
  __syncthreads();
  float a = att[bs];
  if (t < T_) {
    float acc = 0.f;
    for (int c = 0; c < 256; c++) acc += row[c] * ow[c * T_ + t];
    logits[(size_t)bs * T_ + t] = a * acc + ob[t];
  }
}

// ---------------- Viterbi ----------------
__global__ __launch_bounds__(64)
void k_viterbi(const float* __restrict__ logits, const float* __restrict__ start,
               const float* __restrict__ endv, const float* __restrict__ trans,
               float* __restrict__ tags)
{
  __shared__ float sc[16];
  __shared__ float str[169];
  __shared__ unsigned char hist[255 * 13];
  __shared__ int tg[256];
  int b = blockIdx.x, t = threadIdx.x;
  for (int i = t; i < 169; i += 64) str[i] = trans[i];
  if (t < 13) sc[t] = start[t] + logits[((size_t)b * 256) * 13 + t];
  __syncthreads();
  for (int s = 1; s < 256; s++) {
    float best = -1e30f; int bi = 0;
    if (t < 13) {
      best = sc[0] + str[t]; bi = 0;
      for (int i = 1; i < 13; i++) {
        float v = sc[i] + str[i * 13 + t];
        if (v > best) { best = v; bi = i; }
      }
    }
    __syncthreads();
    if (t < 13) {
      sc[t] = best + logits[((size_t)b * 256 + s) * 13 + t];
      hist[(s - 1) * 13 + t] = (unsigned char)bi;
    }
    __syncthreads();
  }
  if (t == 0) {
    float best = sc[0] + endv[0]; int last = 0;
    for (int j = 1; j < 13; j++) {
      float v = sc[j] + endv[j];
      if (v > best) { best = v; last = j; }
    }
    tg[255] = last;
    int cur = last;
    for (int s = 254; s >= 0; s--) { cur = hist[s * 13 + cur]; tg[s] = cur; }
  }
  __syncthreads();
  for (int s = t; s < 256; s += 64) tags[b * 256 + s] = (float)tg[s];
}

// ---------------- launch ----------------
extern "C" void kernel_launch(void* const* d_in, const int* in_sizes, int n_in,
                              void* d_out, int out_size, void* d_ws, size_t ws_size,
                              hipStream_t stream)
{
  const int*   x     = (const int*)  d_in[0];
  const float* pos   = (const float*)d_in[1];
  const float* emb   = (const float*)d_in[2];
  const float* Wih0  = (const float*)d_in[3];
  const float* Whh0  = (const float*)d_in[4];
  const float* b0    = (const float*)d_in[5];
  const float* Wih1  = (const float*)d_in[6];
  const float* Whh1  = (const float*)d_in[7];
  const float* b1    = (const float*)d_in[8];
  const float* fc1w  = (const float*)d_in[9];
  const float* fc1b  = (const float*)d_in[10];
  const float* fc2w  = (const float*)d_in[11];
  const float* fc2b  = (const float*)d_in[12];
  const float* plng  = (const float*)d_in[13];
  const float* plnb  = (const float*)d_in[14];
  const float* condw = (const float*)d_in[15];
  const float* condb = (const float*)d_in[16];
  const float* clnw  = (const float*)d_in[17];
  const float* clnb  = (const float*)d_in[18];
  const float* clnwd = (const float*)d_in[19];
  const float* clnbd = (const float*)d_in[20];
  const float* wq    = (const float*)d_in[21];
  const float* bq    = (const float*)d_in[22];
  const float* wk    = (const float*)d_in[23];
  const float* bk    = (const float*)d_in[24];
  const float* wv    = (const float*)d_in[25];
  const float* bv    = (const float*)d_in[26];
  const float* atlng = (const float*)d_in[27];
  const float* atlnb = (const float*)d_in[28];
  const float* alw   = (const float*)d_in[29];
  const float* alb   = (const float*)d_in[30];
  const float* ow    = (const float*)d_in[31];
  const float* ob    = (const float*)d_in[32];
  const float* cstart= (const float*)d_in[33];
  const float* cend  = (const float*)d_in[34];
  const float* ctrans= (const float*)d_in[35];

  const size_t BS = (size_t)B_ * S_;   // 16384
  float* ws = (float*)d_ws;
  float* r1   = ws;                    // embA hi/lo -> out_cond
  float* xg   = r1 + 5242880;          // fp32 pre-gates [2][S][B][unit*4+gate]
  float* l0r  = xg + 33554432;         // l0 hi/lo -> lstm1 exchange -> outn
  float* l1r  = l0r + 8388608;         // lstm0 exchange -> l1 hi/lo
  float* pos_out  = l1r + 8388608;
  float* wvec     = pos_out + 16384;
  float* bbvec    = wvec + 16384;
  float* sentence = bbvec + 16384;
  float* attv     = sentence + 16384;
  unsigned* flags = (unsigned*)(attv + 16384);     // (unused; layout kept)
  u16* whhh0 = (u16*)(flags + 65536);              // Whh splits: 4 x 524288 u16
  u16* whhl0 = whhh0 + 524288;
  u16* whhh1 = whhl0 + 524288;
  u16* whhl1 = whhh1 + 524288;
  u16* wih0h = whhl1 + 524288;                     // [2][1024][320] (row-permuted)
  u16* wih0l = wih0h + 655360;
  u16* wih1h = wih0l + 655360;                     // [2][1024][512] (row-permuted)
  u16* wih1l = wih1h + 1048576;
  u16* condTh = wih1l + 1048576;                   // [256][512]
  u16* condTl = condTh + 131072;
  float* b0p  = (float*)(condTl + 131072);         // permuted biases [2][1024]
  float* b1p  = b0p + 2048;

  u16* embh = (u16*)r1;
  u16* embl = embh + 5242880;
  float* out_cond = r1;
  u16* l0h = (u16*)l0r;
  u16* l0l = l0h + 8388608;
  u16* l1h = (u16*)l1r;
  u16* l1l = l1h + 8388608;
  u32* hb0 = (u32*)l1r;                 // lstm0 exchange (l1r free until lstm1 hout)
  u32* hb1 = (u32*)l0r;                 // lstm1 exchange (l0 consumed by bgemm1)
  const size_t HBBYTES = (size_t)32 * S_ * 1024 * sizeof(u32);  // 33,554,432 B
  float* outn = l0r;
  float* logits = (float*)d_out;
  float* tags   = logits + BS * T_;

  // sentinel-fill lstm0 exchange region (l1r untouched until lstm0)
  hipMemsetAsync(hb0, 0x7F, HBBYTES, stream);

  k_embed <<<dim3(B_ * S_), dim3(64), 0, stream>>>(x, emb, embh, embl);
  k_cvtbf2<<<dim3(2048), dim3(256), 0, stream>>>(Whh0, whhh0, whhl0, 2 * G4_ * H_);
  k_cvtbf2<<<dim3(2048), dim3(256), 0, stream>>>(Whh1, whhh1, whhl1, 2 * G4_ * H_);
  k_cvtpad<<<dim3(2048), dim3(256), 0, stream>>>(Wih0, wih0h, wih0l, 300, 320, 1);
  k_cvtpad<<<dim3(2048), dim3(256), 0, stream>>>(Wih1, wih1h, wih1l, 512, 512, 1);
  k_permb <<<dim3(8),    dim3(256), 0, stream>>>(b0, b0p);
  k_permb <<<dim3(8),    dim3(256), 0, stream>>>(b1, b1p);
  k_cvtT  <<<dim3(256),  dim3(256), 0, stream>>>(condw, condTh, condTl);

  // layer-0 pre-gates (unit-major via permuted W rows; coalesced epilogue)
  k_bgemm<<<dim3(8, 128, 2), dim3(256), 0, stream>>>(
      embh, embl, wih0h, wih0l, b0p, xg, 320, G4_, 1,
      (long)G4_ * 320, (long)G4_, (long)BS * G4_);
  k_lstm_mfma<<<dim3(256), dim3(256), 0, stream>>>(
      xg, whhh0, whhl0, l0h, l0l, hb0);

  // layer-1 pre-gates
  k_bgemm<<<dim3(8, 128, 2), dim3(256), 0, stream>>>(
      l0h, l0l, wih1h, wih1l, b1p, xg, 512, G4_, 1,
      (long)G4_ * 512, (long)G4_, (long)BS * G4_);
  // sentinel-fill lstm1 exchange region (l0h just consumed by the bgemm above)
  hipMemsetAsync(hb1, 0x7F, HBBYTES, stream);
  k_lstm_mfma<<<dim3(256), dim3(256), 0, stream>>>(
      xg, whhh1, whhl1, l1h, l1l, hb1);

  // cond projection (permute=0)
  k_bgemm<<<dim3(2, 128, 1), dim3(256), 0, stream>>>(
      l1h, l1l, condTh, condTl, condb, out_cond, 512, 256, 0, 0, 0, 0);

  k_pos <<<dim3(B_), dim3(256), 0, stream>>>(pos, fc1w, fc1b, fc2w, fc2b, plng, plnb, pos_out);
  k_clnA<<<dim3(B_), dim3(256), 0, stream>>>(pos_out, clnwd, clnbd, clnw, clnb, wvec, bbvec);
  k_clnB<<<dim3(B_ * S_), dim3(256), 0, stream>>>(out_cond, wvec, bbvec, alw, alb, outn, sentence);
  k_att <<<dim3(B_), dim3(256), 0, stream>>>(sentence, wq, bq, wk, bk, wv, bv, atlng, atlnb, attv);
  k_out <<<dim3(B_ * S_), dim3(64), 0, stream>>>(outn, attv, ow, ob, logits);
  k_viterbi<<<dim3(B_), dim3(64), 0, stream>>>(logits, cstart, cend, ctrans, tags);
}

// Round 4
// 2575.839 us; speedup vs baseline: 1.0537x; 1.0537x over previous
//
#include <hip/hip_runtime.h>
#include <math.h>

// BiLSTM-CRF, round 15: full-width MFMA islands (16 real batches), cooperative
// pull, single barrier per step.
// r14 post-mortem: per-wave private pulls = 4x fabric traffic -> regression.
// r11-r14 showed the step is additive-work bound; the 4-batch islands wasted
// 12/16 MFMA columns (4x redundant MFMA/cell/xg/pull). This round:
// - 8 islands (2 dir x 4 batch-groups of 16) x 16 unit-slices = 128 WGs.
// - wave = 16 rows (4 units x 4 gates) x 16 batches: 24 MFMAs/step in 3
//   independent 8-deep chains; in-lane cell, 1 (unit,batch) per lane.
// - WG-cooperative 16KB slab pull (8 u64/thread), sentinel spin (r12 protocol).
// - LDS slab XOR-swizzled (16-way bank conflict -> free), double-buffered ->
//   ONE __syncthreads per step.
// - hout u64-packed via 3 shfls (kills r13 write amplification).
// B=64 S=256 V=50000 E=300 H=256 T=13
#define B_    64
#define S_    256
#define E_    300
#define H_    256
#define T_    13
#define G4_   1024   // 4*H
#define D2H_  512    // 2*H

typedef short bf16x8 __attribute__((ext_vector_type(8)));   // 8 bf16 in 4 VGPRs
typedef float f32x4  __attribute__((ext_vector_type(4)));
typedef unsigned short u16;
typedef unsigned int   u32;
typedef unsigned long long u64;

#define SENT32 0x7F7F7F7Fu    // memset(0x7F) pattern; impossible packed-h dword

__device__ __forceinline__ float sigf(float x)   { return __builtin_amdgcn_rcpf(1.f + __expf(-x)); }
__device__ __forceinline__ float tanhf_(float x) { return __builtin_amdgcn_rcpf(1.f + __expf(-2.f*x))*2.f - 1.f; }

__device__ __forceinline__ u16 f2bf(float f) {
  union { float f; unsigned u; } v; v.f = f;
  unsigned r = v.u + 0x7fff + ((v.u >> 16) & 1);   // RNE
  return (u16)(r >> 16);
}
__device__ __forceinline__ float bf2f(u16 h) {
  union { unsigned u; float f; } v; v.u = ((unsigned)h) << 16;
  return v.f;
}

// coherent (agent-scope, relaxed) accessors
__device__ __forceinline__ u64 cload64(const u64* p) {
  return __hip_atomic_load(p, __ATOMIC_RELAXED, __HIP_MEMORY_SCOPE_AGENT);
}
__device__ __forceinline__ void cstore32(u32* p, u32 v) {
  __hip_atomic_store(p, v, __ATOMIC_RELAXED, __HIP_MEMORY_SCOPE_AGENT);
}

// ---------------- embedding gather -> bf16 hi/lo, K padded 300->320 ----------------
__global__ __launch_bounds__(64)
void k_embed(const int* __restrict__ x, const float* __restrict__ emb,
             u16* __restrict__ oh, u16* __restrict__ ol) {
  int bs = blockIdx.x;
  int xv = x[bs];
  const float4* src = (const float4*)(emb + (size_t)xv * E_);
  u64* dh = (u64*)(oh + (size_t)bs * 320);
  u64* dl = (u64*)(ol + (size_t)bs * 320);
  for (int q = threadIdx.x; q < 80; q += 64) {
    float4 v = (q < 75) ? src[q] : make_float4(0.f, 0.f, 0.f, 0.f);
    u16 hh[4], ll[4];
    float vv[4] = {v.x, v.y, v.z, v.w};
    #pragma unroll
    for (int j = 0; j < 4; j++) {
      hh[j] = f2bf(vv[j]);
      ll[j] = f2bf(vv[j] - bf2f(hh[j]));
    }
    dh[q] = (u64)hh[0] | ((u64)hh[1] << 16) | ((u64)hh[2] << 32) | ((u64)hh[3] << 48);
    dl[q] = (u64)ll[0] | ((u64)ll[1] << 16) | ((u64)ll[2] << 32) | ((u64)ll[3] << 48);
  }
}

// ---------------- fp32 -> bf16 hi/lo split (flat) ----------------
__global__ __launch_bounds__(256)
void k_cvtbf2(const float* __restrict__ w, u16* __restrict__ hi, u16* __restrict__ lo, int n) {
  int i = blockIdx.x * 256 + threadIdx.x;
  if (i < n) {
    float v = w[i];
    u16 h = f2bf(v);
    hi[i] = h;
    lo[i] = f2bf(v - bf2f(h));
  }
}

// ---------------- fp32 -> bf16 hi/lo, K padding, optional row permute -------------
// perm=1: source row (d, gate*256+unit) lands at buffer row (d, unit*4+gate),
// so the GEMM's output columns come out unit-major with a COALESCED epilogue.
__global__ __launch_bounds__(256)
void k_cvtpad(const float* __restrict__ w, u16* __restrict__ hi, u16* __restrict__ lo,
              int Ksrc, int Kpad, int perm) {
  int r = blockIdx.x;
  int rl = r & 1023, dd = r >> 10;
  int ro = perm ? ((dd << 10) | ((rl & 255) << 2) | (rl >> 8)) : r;
  for (int k = threadIdx.x; k < Kpad; k += 256) {
    float v = (k < Ksrc) ? w[(size_t)r * Ksrc + k] : 0.f;
    u16 h = f2bf(v);
    hi[(size_t)ro * Kpad + k] = h;
    lo[(size_t)ro * Kpad + k] = f2bf(v - bf2f(h));
  }
}

// ---------------- bias permute: (d, gate*256+unit) -> (d, unit*4+gate) ------------
__global__ __launch_bounds__(256)
void k_permb(const float* __restrict__ b, float* __restrict__ bp) {
  int i = blockIdx.x * 256 + threadIdx.x;      // 0..2047
  int rl = i & 1023, dd = i >> 10;
  bp[(dd << 10) | ((rl & 255) << 2) | (rl >> 8)] = b[i];
}

// ---------------- cond_w (512,256) -> transposed hi/lo (256,512) ----------------
__global__ __launch_bounds__(256)
void k_cvtT(const float* __restrict__ w, u16* __restrict__ hi, u16* __restrict__ lo) {
  int n = blockIdx.x;
  for (int k = threadIdx.x; k < 512; k += 256) {
    float v = w[(size_t)k * 256 + n];
    u16 h = f2bf(v);
    hi[(size_t)n * 512 + k] = h;
    lo[(size_t)n * 512 + k] = f2bf(v - bf2f(h));
  }
}

// ---------------- split-bf16 MFMA GEMM: C = A @ W^T + bias (round-12 form) --------
__global__ __launch_bounds__(256)
void k_bgemm(const u16* __restrict__ Ahi, const u16* __restrict__ Alo,
             const u16* __restrict__ Whi, const u16* __restrict__ Wlo,
             const float* __restrict__ bias, float* __restrict__ C,
             int K, int N, int permute, long wStride, long bStride, long cStride)
{
  __shared__ u16 Ash[2][128 * 40];
  __shared__ u16 Wsh[2][128 * 40];

  int tid = threadIdx.x;
  int d   = blockIdx.z;
  int n0  = blockIdx.x * 128, m0 = blockIdx.y * 128;
  int lane = tid & 63;
  int w    = tid >> 6;
  int l15  = lane & 15;
  int quad = lane >> 4;
  int mh = (w >> 1) * 64, nh = (w & 1) * 64;

  int comp = tid >> 7, row = tid & 127;
  int gr = m0 + row;
  int ar = permute ? ((gr & 63) * S_ + (gr >> 6)) : gr;
  const u16* Asrc = (comp ? Alo : Ahi) + (size_t)ar * K;
  const u16* Wsrc = (comp ? Wlo : Whi) + (size_t)d * wStride + (size_t)(n0 + row) * K;
  u16* AshC = &Ash[comp][row * 40];
  u16* WshC = &Wsh[comp][row * 40];

  f32x4 acc[4][4];
  #pragma unroll
  for (int mt = 0; mt < 4; mt++)
    #pragma unroll
    for (int nt = 0; nt < 4; nt++) acc[mt][nt] = (f32x4)(0.f);

  for (int k0 = 0; k0 < K; k0 += 32) {
    float4 a0 = *(const float4*)(Asrc + k0);
    float4 a1 = *(const float4*)(Asrc + k0 + 8);
    float4 a2 = *(const float4*)(Asrc + k0 + 16);
    float4 a3 = *(const float4*)(Asrc + k0 + 24);
    float4 w0 = *(const float4*)(Wsrc + k0);
    float4 w1 = *(const float4*)(Wsrc + k0 + 8);
    float4 w2 = *(const float4*)(Wsrc + k0 + 16);
    float4 w3 = *(const float4*)(Wsrc + k0 + 24);
    __syncthreads();
    *(float4*)(AshC)      = a0; *(float4*)(AshC + 8)  = a1;
    *(float4*)(AshC + 16) = a2; *(float4*)(AshC + 24) = a3;
    *(float4*)(WshC)      = w0; *(float4*)(WshC + 8)  = w1;
    *(float4*)(WshC + 16) = w2; *(float4*)(WshC + 24) = w3;
    __syncthreads();

    bf16x8 ah[4], al[4], bh[4], bl[4];
    #pragma unroll
    for (int mt = 0; mt < 4; mt++) {
      int rr = mh + mt * 16 + l15;
      ah[mt] = *(const bf16x8*)&Ash[0][rr * 40 + quad * 8];
      al[mt] = *(const bf16x8*)&Ash[1][rr * 40 + quad * 8];
    }
    #pragma unroll
    for (int nt = 0; nt < 4; nt++) {
      int rr = nh + nt * 16 + l15;
      bh[nt] = *(const bf16x8*)&Wsh[0][rr * 40 + quad * 8];
      bl[nt] = *(const bf16x8*)&Wsh[1][rr * 40 + quad * 8];
    }
    #pragma unroll
    for (int mt = 0; mt < 4; mt++)
      #pragma unroll
      for (int nt = 0; nt < 4; nt++) {
        acc[mt][nt] = __builtin_amdgcn_mfma_f32_16x16x32_bf16(ah[mt], bh[nt], acc[mt][nt], 0, 0, 0);
        acc[mt][nt] = __builtin_amdgcn_mfma_f32_16x16x32_bf16(ah[mt], bl[nt], acc[mt][nt], 0, 0, 0);
        acc[mt][nt] = __builtin_amdgcn_mfma_f32_16x16x32_bf16(al[mt], bh[nt], acc[mt][nt], 0, 0, 0);
      }
  }

  const float* biasd = bias + (size_t)d * bStride;
  float* Cd = C + (size_t)d * cStride;
  #pragma unroll
  for (int nt = 0; nt < 4; nt++) {
    int cn = n0 + nh + nt * 16 + l15;
    float bv = biasd[cn];
    #pragma unroll
    for (int mt = 0; mt < 4; mt++) {
      int mr = m0 + mh + mt * 16 + quad * 4;
      #pragma unroll
      for (int j = 0; j < 4; j++)
        Cd[(size_t)(mr + j) * N + cn] = acc[mt][nt][j] + bv;
    }
  }
}

// ---------------- full-width split-bf16 MFMA LSTM ----------------
// 128 WGs: blockIdx.x = us*8 + isl; isl = d*4 + ig (16 slices of an island on
// one XCD under round-robin; heuristic only). Island = 16 batches ig*16..+15.
// Wave w: units u0 = us*16 + w*4 .. +3, all 4 gates; 16 real batches (l15).
// A row m = lu*4+gate -> Whh row gate*256 + (u0+lu). C[row=quad*4+j][col=l15]
// = gate j of unit u0+quad, batch bg0+l15 -> in-lane cell, no redundancy.
// Exchange slab per (island, step): u32[batch 0..15][unit 0..255] = hh|hl<<16.
// Cooperative pull: thread t spins/pulls u64s t+256r (r=0..7), unpacks into
// XOR-swizzled, double-buffered LDS slab. ONE barrier per step.
__global__ __launch_bounds__(256, 1)
void k_lstm_mfma(const float* __restrict__ xg,
                 const u16* __restrict__ Whi, const u16* __restrict__ Wlo,
                 u16* __restrict__ houth, u16* __restrict__ houtl,
                 u32* __restrict__ hbx)
{
  __shared__ __align__(16) u16 hsh[2][16 * 256];   // 2 x 8KB hi slabs
  __shared__ __align__(16) u16 hsl[2][16 * 256];   // 2 x 8KB lo slabs

  int tid  = threadIdx.x;
  int us   = blockIdx.x >> 3;        // unit slice 0..15
  int isl  = blockIdx.x & 7;         // island = d*4 + ig
  int d    = isl >> 2;
  int bg0  = (isl & 3) * 16;         // batch base
  int lane = tid & 63;
  int w    = tid >> 6;
  int l15  = lane & 15;
  int quad = lane >> 4;
  int u0   = us * 16 + w * 4;        // wave's first unit
  int uq   = u0 + quad;              // this lane's unit (cell view)

  // A-frags: lane holds A[m=l15][k=quad*8+j]; m = lu*4+gate
  bf16x8 afh[8], afl[8];
  {
    size_t rowb = ((size_t)d * G4_ + (size_t)(l15 & 3) * 256 + u0 + (l15 >> 2)) * H_;
    #pragma unroll
    for (int kt = 0; kt < 8; kt++) {
      afh[kt] = *(const bf16x8*)(Whi + rowb + kt * 32 + quad * 8);
      afl[kt] = *(const bf16x8*)(Wlo + rowb + kt * 32 + quad * 8);
    }
  }
  #pragma unroll
  for (int kt = 0; kt < 8; kt++) {
    asm volatile("" : "+v"(afh[kt]));
    asm volatile("" : "+v"(afl[kt]));
  }

  float cc = 0.f;

  const float* xgd = xg + (size_t)d * S_ * B_ * G4_;
  u32* hb = hbx + (size_t)isl * S_ * 4096;

  for (int it = 0; it < S_; it++) {
    int s = d ? (S_ - 1 - it) : it;
    int p = (it + 1) & 1;            // slab parity for step it-1 data

    // acc init from unit-major xg (issued early; hides under the spin)
    f32x4 accA, accB1, accB2;
    accA  = *(const f32x4*)(xgd + ((size_t)s * B_ + bg0 + l15) * G4_ + (size_t)uq * 4);
    accB1 = (f32x4)(0.f);
    accB2 = (f32x4)(0.f);

    if (it > 0) {
      // cooperative pull of the 16KB island slab; sentinel spin
      const u64* src = (const u64*)(hb + (size_t)(it - 1) * 4096);
      u64 v[8];
      #pragma unroll
      for (int r = 0; r < 8; r++) v[r] = cload64(src + tid + 256 * r);
      #pragma unroll
      for (int r = 0; r < 8; r++) {
        while (((u32)v[r] == SENT32) | ((u32)(v[r] >> 32) == SENT32)) {
          __builtin_amdgcn_s_sleep(1);
          v[r] = cload64(src + tid + 256 * r);
        }
      }
      // unpack into swizzled LDS slab: u64 j -> batch j>>7, units (j&127)*2,+1
      char* sh = (char*)hsh[p];
      char* sl = (char*)hsl[p];
      #pragma unroll
      for (int r = 0; r < 8; r++) {
        int j = tid + 256 * r;
        int batch = j >> 7;
        int off = (batch * 512 + (j & 127) * 4) ^ ((batch & 7) << 4);
        u64 vv = v[r];
        *(u32*)(sh + off) = ((u32)vv & 0xFFFFu) | (((u32)(vv >> 32) & 0xFFFFu) << 16);
        *(u32*)(sl + off) = (((u32)(vv >> 16)) & 0xFFFFu) | ((u32)(vv >> 48) << 16);
      }
      __syncthreads();   // slab(it-1) complete (single barrier per step)

      const char* sh2 = (const char*)hsh[p];
      const char* sl2 = (const char*)hsl[p];
      #pragma unroll
      for (int kt = 0; kt < 8; kt++) {
        int coff = (l15 * 512 + kt * 64 + quad * 16) ^ ((l15 & 7) << 4);
        bf16x8 bh = *(const bf16x8*)(sh2 + coff);
        bf16x8 bl = *(const bf16x8*)(sl2 + coff);
        accA  = __builtin_amdgcn_mfma_f32_16x16x32_bf16(afh[kt], bh, accA,  0, 0, 0);
        accB1 = __builtin_amdgcn_mfma_f32_16x16x32_bf16(afh[kt], bl, accB1, 0, 0, 0);
        accB2 = __builtin_amdgcn_mfma_f32_16x16x32_bf16(afl[kt], bh, accB2, 0, 0, 0);
      }
    }

    // in-lane cell: g[j] = gate j (i,f,g,o) of unit uq, batch bg0+l15
    f32x4 g = accA + accB1 + accB2;
    cc = sigf(g[1]) * cc + sigf(g[0]) * tanhf_(g[2]);
    float h = sigf(g[3]) * tanhf_(cc);
    u16 hh = f2bf(h), hl = f2bf(h - bf2f(hh));
    u32 pk = (u32)hh | ((u32)hl << 16);
    cstore32(hb + (size_t)it * 4096 + l15 * 256 + uq, pk);   // publish ASAP

    // hout: pack 4 units via shfl; quad-0 lanes store u64 hi + u64 lo
    u32 q1 = __shfl(pk, l15 + 16);
    u32 q2 = __shfl(pk, l15 + 32);
    u32 q3 = __shfl(pk, l15 + 48);
    if (quad == 0) {
      u64 hi64 = (u64)(pk & 0xFFFFu)        | ((u64)(q1 & 0xFFFFu) << 16)
               | ((u64)(q2 & 0xFFFFu) << 32) | ((u64)(q3 & 0xFFFFu) << 48);
      u64 lo64 = (u64)(pk >> 16)            | ((u64)(q1 >> 16) << 16)
               | ((u64)(q2 >> 16) << 32)     | ((u64)(q3 >> 16) << 48);
      size_t ho = ((size_t)(bg0 + l15) * S_ + s) * D2H_ + d * H_ + u0;
      *(u64*)(houth + ho) = hi64;
      *(u64*)(houtl + ho) = lo64;
    }
    // no end barrier: double-buffered slab; next iter writes other parity,
    // and its barrier orders any 2-iteration-apart reuse.
  }
}

// ---------------- block reduction helpers ----------------
__device__ __forceinline__ float bsum(float v, float* sb) {
  int t = threadIdx.x;
  sb[t] = v; __syncthreads();
  for (int s = 128; s; s >>= 1) { if (t < s) sb[t] += sb[t + s]; __syncthreads(); }
  float r = sb[0]; __syncthreads(); return r;
}
__device__ __forceinline__ float bmax(float v, float* sb) {
  int t = threadIdx.x;
  sb[t] = v; __syncthreads();
  for (int s = 128; s; s >>= 1) { if (t < s) sb[t] = fmaxf(sb[t], sb[t + s]); __syncthreads(); }
  float r = sb[0]; __syncthreads(); return r;
}

// ---------------- pos branch ----------------
__global__ __launch_bounds__(256)
void k_pos(const float* __restrict__ pos, const float* __restrict__ fc1w, const float* __restrict__ fc1b,
           const float* __restrict__ fc2w, const float* __restrict__ fc2b,
           const float* __restrict__ lng, const float* __restrict__ lnb, float* __restrict__ pos_out)
{
  __shared__ float sp[256], sh[256], sb[256];
  int b = blockIdx.x, t = threadIdx.x;
  sp[t] = pos[b * 256 + t];
  __syncthreads();
  float a1 = fc1b[t];
  for (int s = 0; s < 256; s++) a1 += sp[s] * fc1w[s * 256 + t];
  a1 = fmaxf(a1, 0.f);
  sh[t] = a1; __syncthreads();
  float a2 = fc2b[t] + sp[t];
  for (int s = 0; s < 256; s++) a2 += sh[s] * fc2w[s * 256 + t];
  float m   = bsum(a2, sb) * (1.f / 256.f);
  float cen = a2 - m;
  float var = bsum(cen * cen, sb) * (1.f / 256.f);
  pos_out[b * 256 + t] = cen * rsqrtf(var + 1e-5f) * lng[t] + lnb[t];
}

// ---------------- CLN stage A ----------------
__global__ __launch_bounds__(256)
void k_clnA(const float* __restrict__ pos_out, const float* __restrict__ wd, const float* __restrict__ bd,
            const float* __restrict__ cw, const float* __restrict__ cb,
            float* __restrict__ wvec, float* __restrict__ bbvec)
{
  __shared__ float sp[256];
  int b = blockIdx.x, t = threadIdx.x;
  sp[t] = pos_out[b * 256 + t];
  __syncthreads();
  const float4* wdr = (const float4*)(wd + (size_t)t * 256);
  const float4* bdr = (const float4*)(bd + (size_t)t * 256);
  float aw = 0.f, ab = 0.f;
  for (int q = 0; q < 64; q++) {
    float4 w4 = wdr[q], b4 = bdr[q];
    float s0 = sp[q*4], s1 = sp[q*4+1], s2 = sp[q*4+2], s3 = sp[q*4+3];
    aw += s0*w4.x + s1*w4.y + s2*w4.z + s3*w4.w;
    ab += s0*b4.x + s1*b4.y + s2*b4.z + s3*b4.w;
  }
  wvec [b * 256 + t] = aw + cw[t];
  bbvec[b * 256 + t] = ab + cb[t];
}

// ---------------- CLN stage B + sentence dot ----------------
__global__ __launch_bounds__(256)
void k_clnB(const float* __restrict__ oc, const float* __restrict__ wvec, const float* __restrict__ bbvec,
            const float* __restrict__ alw, const float* __restrict__ alb,
            float* __restrict__ outn, float* __restrict__ sentence)
{
  __shared__ float sb[256];
  int bs = blockIdx.x, t = threadIdx.x;
  int b = bs >> 8;
  float v   = oc[(size_t)bs * 256 + t];
  float m   = bsum(v, sb) * (1.f / 256.f);
  float cen = v - m;
  float var = bsum(cen * cen, sb) * (1.f / 256.f);
  float o   = cen * rsqrtf(var + 1e-12f) * wvec[b * 256 + t] + bbvec[b * 256 + t];
  outn[(size_t)bs * 256 + t] = o;
  float sv = bsum(o * alw[t], sb);
  if (t == 0) sentence[bs] = sv + alb[0];
}

// ---------------- attention ----------------
__global__ __launch_bounds__(256)
void k_att(const float* __restrict__ sentence,
           const float* __restrict__ wq, const float* __restrict__ bq,
           const float* __restrict__ wk, const float* __restrict__ bk,
           const float* __restrict__ wv, const float* __restrict__ bv,
           const float* __restrict__ lng, const float* __restrict__ lnb,
           float* __restrict__ att)
{
  __shared__ float ss[256], sb[256];
  int b = blockIdx.x, t = threadIdx.x;
  ss[t] = sentence[b * 256 + t];
  __syncthreads();
  float q = bq[t], k = bk[t], vv = bv[t];
  for (int s = 0; s < 256; s++) {
    float sv = ss[s];
    q  += sv * wq[s * 256 + t];
    k  += sv * wk[s * 256 + t];
    vv += sv * wv[s * 256 + t];
  }
  float x  = q * k * (1.f / 16.f);
  float mx = bmax(x, sb);
  float e  = expf(x - mx);
  float sm = bsum(e, sb);
  float a  = (e / sm) * vv;
  float m   = bsum(a, sb) * (1.f / 256.f);
  float cen = a - m;
  float var = bsum(cen * cen, sb) * (1.f / 256.f);
  att[b * 256 + t] = cen * rsqrtf(var + 1e-5f) * lng[t] + lnb[t];
}

// ---------------- logits ----------------
__global__ __launch_bounds__(64)
void k_out(const float* __restrict__ outn, const float* __restrict__ att,
           const float* __restrict__ ow, const float* __restrict__ ob,
           float* __restrict__ logits)
{
  __shared__ float row[256];
  int bs = blockIdx.x, t = threadIdx.x;
  ((float4*)row)[t] = ((const float4*)(outn + (size_t)bs * 256))[t];
  __syncthreads();
  float a = att[bs];
  if (t < T_) {
    float acc = 0.f;
    for (int c = 0; c < 256; c++) acc += row[c] * ow[c * T_ + t];
    logits[(size_t)bs * T_ + t] = a * acc + ob[t];
  }
}

// ---------------- Viterbi ----------------
__global__ __launch_bounds__(64)
void k_viterbi(const float* __restrict__ logits, const float* __restrict__ start,
               const float* __restrict__ endv, const float* __restrict__ trans,
               float* __restrict__ tags)
{
  __shared__ float sc[16];
  __shared__ float str[169];
  __shared__ unsigned char hist[255 * 13];
  __shared__ int tg[256];
  int b = blockIdx.x, t = threadIdx.x;
  for (int i = t; i < 169; i += 64) str[i] = trans[i];
  if (t < 13) sc[t] = start[t] + logits[((size_t)b * 256) * 13 + t];
  __syncthreads();
  for (int s = 1; s < 256; s++) {
    float best = -1e30f; int bi = 0;
    if (t < 13) {
      best = sc[0] + str[t]; bi = 0;
      for (int i = 1; i < 13; i++) {
        float v = sc[i] + str[i * 13 + t];
        if (v > best) { best = v; bi = i; }
      }
    }
    __syncthreads();
    if (t < 13) {
      sc[t] = best + logits[((size_t)b * 256 + s) * 13 + t];
      hist[(s - 1) * 13 + t] = (unsigned char)bi;
    }
    __syncthreads();
  }
  if (t == 0) {
    float best = sc[0] + endv[0]; int last = 0;
    for (int j = 1; j < 13; j++) {
      float v = sc[j] + endv[j];
      if (v > best) { best = v; last = j; }
    }
    tg[255] = last;
    int cur = last;
    for (int s = 254; s >= 0; s--) { cur = hist[s * 13 + cur]; tg[s] = cur; }
  }
  __syncthreads();
  for (int s = t; s < 256; s += 64) tags[b * 256 + s] = (float)tg[s];
}

// ---------------- launch ----------------
extern "C" void kernel_launch(void* const* d_in, const int* in_sizes, int n_in,
                              void* d_out, int out_size, void* d_ws, size_t ws_size,
                              hipStream_t stream)
{
  const int*   x     = (const int*)  d_in[0];
  const float* pos   = (const float*)d_in[1];
  const float* emb   = (const float*)d_in[2];
  const float* Wih0  = (const float*)d_in[3];
  const float* Whh0  = (const float*)d_in[4];
  const float* b0    = (const float*)d_in[5];
  const float* Wih1  = (const float*)d_in[6];
  const float* Whh1  = (const float*)d_in[7];
  const float* b1    = (const float*)d_in[8];
  const float* fc1w  = (const float*)d_in[9];
  const float* fc1b  = (const float*)d_in[10];
  const float* fc2w  = (const float*)d_in[11];
  const float* fc2b  = (const float*)d_in[12];
  const float* plng  = (const float*)d_in[13];
  const float* plnb  = (const float*)d_in[14];
  const float* condw = (const float*)d_in[15];
  const float* condb = (const float*)d_in[16];
  const float* clnw  = (const float*)d_in[17];
  const float* clnb  = (const float*)d_in[18];
  const float* clnwd = (const float*)d_in[19];
  const float* clnbd = (const float*)d_in[20];
  const float* wq    = (const float*)d_in[21];
  const float* bq    = (const float*)d_in[22];
  const float* wk    = (const float*)d_in[23];
  const float* bk    = (const float*)d_in[24];
  const float* wv    = (const float*)d_in[25];
  const float* bv    = (const float*)d_in[26];
  const float* atlng = (const float*)d_in[27];
  const float* atlnb = (const float*)d_in[28];
  const float* alw   = (const float*)d_in[29];
  const float* alb   = (const float*)d_in[30];
  const float* ow    = (const float*)d_in[31];
  const float* ob    = (const float*)d_in[32];
  const float* cstart= (const float*)d_in[33];
  const float* cend  = (const float*)d_in[34];
  const float* ctrans= (const float*)d_in[35];

  const size_t BS = (size_t)B_ * S_;   // 16384
  float* ws = (float*)d_ws;
  float* r1   = ws;                    // embA hi/lo -> out_cond
  float* xg   = r1 + 5242880;          // fp32 pre-gates [2][S][B][unit*4+gate]
  float* l0r  = xg + 33554432;         // l0 hi/lo -> lstm1 exchange -> outn
  float* l1r  = l0r + 8388608;         // lstm0 exchange -> l1 hi/lo
  float* pos_out  = l1r + 8388608;
  float* wvec     = pos_out + 16384;
  float* bbvec    = wvec + 16384;
  float* sentence = bbvec + 16384;
  float* attv     = sentence + 16384;
  unsigned* flags = (unsigned*)(attv + 16384);     // (unused; layout kept)
  u16* whhh0 = (u16*)(flags + 65536);              // Whh splits: 4 x 524288 u16
  u16* whhl0 = whhh0 + 524288;
  u16* whhh1 = whhl0 + 524288;
  u16* whhl1 = whhh1 + 524288;
  u16* wih0h = whhl1 + 524288;                     // [2][1024][320] (row-permuted)
  u16* wih0l = wih0h + 655360;
  u16* wih1h = wih0l + 655360;                     // [2][1024][512] (row-permuted)
  u16* wih1l = wih1h + 1048576;
  u16* condTh = wih1l + 1048576;                   // [256][512]
  u16* condTl = condTh + 131072;
  float* b0p  = (float*)(condTl + 131072);         // permuted biases [2][1024]
  float* b1p  = b0p + 2048;

  u16* embh = (u16*)r1;
  u16* embl = embh + 5242880;
  float* out_cond = r1;
  u16* l0h = (u16*)l0r;
  u16* l0l = l0h + 8388608;
  u16* l1h = (u16*)l1r;
  u16* l1l = l1h + 8388608;
  u32* hb0 = (u32*)l1r;                 // lstm0 exchange (l1r free until lstm1 hout)
  u32* hb1 = (u32*)l0r;                 // lstm1 exchange (l0 consumed by bgemm1)
  const size_t HBBYTES = (size_t)8 * S_ * 4096 * sizeof(u32);   // 33,554,432 B
  float* outn = l0r;
  float* logits = (float*)d_out;
  float* tags   = logits + BS * T_;

  // sentinel-fill lstm0 exchange region (l1r untouched until lstm0)
  hipMemsetAsync(hb0, 0x7F, HBBYTES, stream);

  k_embed <<<dim3(B_ * S_), dim3(64), 0, stream>>>(x, emb, embh, embl);
  k_cvtbf2<<<dim3(2048), dim3(256), 0, stream>>>(Whh0, whhh0, whhl0, 2 * G4_ * H_);
  k_cvtbf2<<<dim3(2048), dim3(256), 0, stream>>>(Whh1, whhh1, whhl1, 2 * G4_ * H_);
  k_cvtpad<<<dim3(2048), dim3(256), 0, stream>>>(Wih0, wih0h, wih0l, 300, 320, 1);
  k_cvtpad<<<dim3(2048), dim3(256), 0, stream>>>(Wih1, wih1h, wih1l, 512, 512, 1);
  k_permb <<<dim3(8),    dim3(256), 0, stream>>>(b0, b0p);
  k_permb <<<dim3(8),    dim3(256), 0, stream>>>(b1, b1p);
  k_cvtT  <<<dim3(256),  dim3(256), 0, stream>>>(condw, condTh, condTl);

  // layer-0 pre-gates (unit-major via permuted W rows; coalesced epilogue)
  k_bgemm<<<dim3(8, 128, 2), dim3(256), 0, stream>>>(
      embh, embl, wih0h, wih0l, b0p, xg, 320, G4_, 1,
      (long)G4_ * 320, (long)G4_, (long)BS * G4_);
  k_lstm_mfma<<<dim3(128), dim3(256), 0, stream>>>(
      xg, whhh0, whhl0, l0h, l0l, hb0);

  // layer-1 pre-gates
  k_bgemm<<<dim3(8, 128, 2), dim3(256), 0, stream>>>(
      l0h, l0l, wih1h, wih1l, b1p, xg, 512, G4_, 1,
      (long)G4_ * 512, (long)G4_, (long)BS * G4_);
  // sentinel-fill lstm1 exchange region (l0h just consumed by the bgemm above)
  hipMemsetAsync(hb1, 0x7F, HBBYTES, stream);
  k_lstm_mfma<<<dim3(128), dim3(256), 0, stream>>>(
      xg, whhh1, whhl1, l1h, l1l, hb1);

  // cond projection (permute=0)
  k_bgemm<<<dim3(2, 128, 1), dim3(256), 0, stream>>>(
      l1h, l1l, condTh, condTl, condb, out_cond, 512, 256, 0, 0, 0, 0);

  k_pos <<<dim3(B_), dim3(256), 0, stream>>>(pos, fc1w, fc1b, fc2w, fc2b, plng, plnb, pos_out);
  k_clnA<<<dim3(B_), dim3(256), 0, stream>>>(pos_out, clnwd, clnbd, clnw, clnb, wvec, bbvec);
  k_clnB<<<dim3(B_ * S_), dim3(256), 0, stream>>>(out_cond, wvec, bbvec, alw, alb, outn, sentence);
  k_att <<<dim3(B_), dim3(256), 0, stream>>>(sentence, wq, bq, wk, bk, wv, bv, atlng, atlnb, attv);
  k_out <<<dim3(B_ * S_), dim3(64), 0, stream>>>(outn, attv, ow, ob, logits);
  k_viterbi<<<dim3(B_), dim3(64), 0, stream>>>(logits, cstart, cend, ctrans, tags);
}

// Round 5
// 1882.196 us; speedup vs baseline: 1.4420x; 1.3685x over previous
//
#include <hip/hip_runtime.h>
#include <math.h>

// BiLSTM-CRF, round 16: consolidated r13 + hybrid L2/L3 spin.
// r14/r15 lesson: minimize per-step coherent traffic and producer count ->
// back to 8-WG/4-batch islands (r12/r13 class, best measured). Fixes on r13:
// - shfl-packed 16B hout stores (kills r13's +32MB write amplification)
// - double-buffered LDS slab -> ONE barrier per step
// - full XOR swizzle on slab writes (r13: 1.9e7 bank conflicts)
// - hybrid spin: fast path global_load_dwordx4 sc0 (L2-coherent; pays off if
//   island co-located on one XCD via blockIdx=us*32+isl), fallback after 2
//   tries to agent-scope load (L3, always fresh) -> correct under ANY placement.
// B=64 S=256 V=50000 E=300 H=256 T=13
#define B_    64
#define S_    256
#define E_    300
#define H_    256
#define T_    13
#define G4_   1024   // 4*H
#define D2H_  512    // 2*H

typedef short bf16x8 __attribute__((ext_vector_type(8)));   // 8 bf16 in 4 VGPRs
typedef float f32x4  __attribute__((ext_vector_type(4)));
typedef unsigned int u32x4 __attribute__((ext_vector_type(4)));
typedef unsigned short u16;
typedef unsigned int   u32;
typedef unsigned long long u64;

#define SENT32 0x7F7F7F7Fu    // memset(0x7F) pattern; impossible packed-h dword

__device__ __forceinline__ float sigf(float x)   { return __builtin_amdgcn_rcpf(1.f + __expf(-x)); }
__device__ __forceinline__ float tanhf_(float x) { return __builtin_amdgcn_rcpf(1.f + __expf(-2.f*x))*2.f - 1.f; }

__device__ __forceinline__ u16 f2bf(float f) {
  union { float f; unsigned u; } v; v.f = f;
  unsigned r = v.u + 0x7fff + ((v.u >> 16) & 1);   // RNE
  return (u16)(r >> 16);
}
__device__ __forceinline__ float bf2f(u16 h) {
  union { unsigned u; float f; } v; v.u = ((unsigned)h) << 16;
  return v.f;
}

// coherent accessors
__device__ __forceinline__ u64 cload64(const u64* p) {          // agent (L3) - always fresh
  return __hip_atomic_load(p, __ATOMIC_RELAXED, __HIP_MEMORY_SCOPE_AGENT);
}
__device__ __forceinline__ void cstore32(u32* p, u32 v) {       // agent write-through
  __hip_atomic_store(p, v, __ATOMIC_RELAXED, __HIP_MEMORY_SCOPE_AGENT);
}
__device__ __forceinline__ u32x4 l2load128(const u32* p) {      // L1-bypass, L2-coherent
  u32x4 r;
  asm volatile("global_load_dwordx4 %0, %1, off sc0\n\ts_waitcnt vmcnt(0)"
               : "=v"(r) : "v"(p) : "memory");
  return r;
}

// ---------------- embedding gather -> bf16 hi/lo, K padded 300->320 ----------------
__global__ __launch_bounds__(64)
void k_embed(const int* __restrict__ x, const float* __restrict__ emb,
             u16* __restrict__ oh, u16* __restrict__ ol) {
  int bs = blockIdx.x;
  int xv = x[bs];
  const float4* src = (const float4*)(emb + (size_t)xv * E_);
  u64* dh = (u64*)(oh + (size_t)bs * 320);
  u64* dl = (u64*)(ol + (size_t)bs * 320);
  for (int q = threadIdx.x; q < 80; q += 64) {
    float4 v = (q < 75) ? src[q] : make_float4(0.f, 0.f, 0.f, 0.f);
    u16 hh[4], ll[4];
    float vv[4] = {v.x, v.y, v.z, v.w};
    #pragma unroll
    for (int j = 0; j < 4; j++) {
      hh[j] = f2bf(vv[j]);
      ll[j] = f2bf(vv[j] - bf2f(hh[j]));
    }
    dh[q] = (u64)hh[0] | ((u64)hh[1] << 16) | ((u64)hh[2] << 32) | ((u64)hh[3] << 48);
    dl[q] = (u64)ll[0] | ((u64)ll[1] << 16) | ((u64)ll[2] << 32) | ((u64)ll[3] << 48);
  }
}

// ---------------- fp32 -> bf16 hi/lo split (flat) ----------------
__global__ __launch_bounds__(256)
void k_cvtbf2(const float* __restrict__ w, u16* __restrict__ hi, u16* __restrict__ lo, int n) {
  int i = blockIdx.x * 256 + threadIdx.x;
  if (i < n) {
    float v = w[i];
    u16 h = f2bf(v);
    hi[i] = h;
    lo[i] = f2bf(v - bf2f(h));
  }
}

// ---------------- fp32 -> bf16 hi/lo, K padding, optional row permute -------------
// perm=1: source row (d, gate*256+unit) lands at buffer row (d, unit*4+gate).
__global__ __launch_bounds__(256)
void k_cvtpad(const float* __restrict__ w, u16* __restrict__ hi, u16* __restrict__ lo,
              int Ksrc, int Kpad, int perm) {
  int r = blockIdx.x;
  int rl = r & 1023, dd = r >> 10;
  int ro = perm ? ((dd << 10) | ((rl & 255) << 2) | (rl >> 8)) : r;
  for (int k = threadIdx.x; k < Kpad; k += 256) {
    float v = (k < Ksrc) ? w[(size_t)r * Ksrc + k] : 0.f;
    u16 h = f2bf(v);
    hi[(size_t)ro * Kpad + k] = h;
    lo[(size_t)ro * Kpad + k] = f2bf(v - bf2f(h));
  }
}

// ---------------- bias permute: (d, gate*256+unit) -> (d, unit*4+gate) ------------
__global__ __launch_bounds__(256)
void k_permb(const float* __restrict__ b, float* __restrict__ bp) {
  int i = blockIdx.x * 256 + threadIdx.x;      // 0..2047
  int rl = i & 1023, dd = i >> 10;
  bp[(dd << 10) | ((rl & 255) << 2) | (rl >> 8)] = b[i];
}

// ---------------- cond_w (512,256) -> transposed hi/lo (256,512) ----------------
__global__ __launch_bounds__(256)
void k_cvtT(const float* __restrict__ w, u16* __restrict__ hi, u16* __restrict__ lo) {
  int n = blockIdx.x;
  for (int k = threadIdx.x; k < 512; k += 256) {
    float v = w[(size_t)k * 256 + n];
    u16 h = f2bf(v);
    hi[(size_t)n * 512 + k] = h;
    lo[(size_t)n * 512 + k] = f2bf(v - bf2f(h));
  }
}

// ---------------- split-bf16 MFMA GEMM: C = A @ W^T + bias (coalesced epilogue) ---
__global__ __launch_bounds__(256)
void k_bgemm(const u16* __restrict__ Ahi, const u16* __restrict__ Alo,
             const u16* __restrict__ Whi, const u16* __restrict__ Wlo,
             const float* __restrict__ bias, float* __restrict__ C,
             int K, int N, int permute, long wStride, long bStride, long cStride)
{
  __shared__ u16 Ash[2][128 * 40];
  __shared__ u16 Wsh[2][128 * 40];

  int tid = threadIdx.x;
  int d   = blockIdx.z;
  int n0  = blockIdx.x * 128, m0 = blockIdx.y * 128;
  int lane = tid & 63;
  int w    = tid >> 6;
  int l15  = lane & 15;
  int quad = lane >> 4;
  int mh = (w >> 1) * 64, nh = (w & 1) * 64;

  int comp = tid >> 7, row = tid & 127;
  int gr = m0 + row;
  int ar = permute ? ((gr & 63) * S_ + (gr >> 6)) : gr;
  const u16* Asrc = (comp ? Alo : Ahi) + (size_t)ar * K;
  const u16* Wsrc = (comp ? Wlo : Whi) + (size_t)d * wStride + (size_t)(n0 + row) * K;
  u16* AshC = &Ash[comp][row * 40];
  u16* WshC = &Wsh[comp][row * 40];

  f32x4 acc[4][4];
  #pragma unroll
  for (int mt = 0; mt < 4; mt++)
    #pragma unroll
    for (int nt = 0; nt < 4; nt++) acc[mt][nt] = (f32x4)(0.f);

  for (int k0 = 0; k0 < K; k0 += 32) {
    float4 a0 = *(const float4*)(Asrc + k0);
    float4 a1 = *(const float4*)(Asrc + k0 + 8);
    float4 a2 = *(const float4*)(Asrc + k0 + 16);
    float4 a3 = *(const float4*)(Asrc + k0 + 24);
    float4 w0 = *(const float4*)(Wsrc + k0);
    float4 w1 = *(const float4*)(Wsrc + k0 + 8);
    float4 w2 = *(const float4*)(Wsrc + k0 + 16);
    float4 w3 = *(const float4*)(Wsrc + k0 + 24);
    __syncthreads();
    *(float4*)(AshC)      = a0; *(float4*)(AshC + 8)  = a1;
    *(float4*)(AshC + 16) = a2; *(float4*)(AshC + 24) = a3;
    *(float4*)(WshC)      = w0; *(float4*)(WshC + 8)  = w1;
    *(float4*)(WshC + 16) = w2; *(float4*)(WshC + 24) = w3;
    __syncthreads();

    bf16x8 ah[4], al[4], bh[4], bl[4];
    #pragma unroll
    for (int mt = 0; mt < 4; mt++) {
      int rr = mh + mt * 16 + l15;
      ah[mt] = *(const bf16x8*)&Ash[0][rr * 40 + quad * 8];
      al[mt] = *(const bf16x8*)&Ash[1][rr * 40 + quad * 8];
    }
    #pragma unroll
    for (int nt = 0; nt < 4; nt++) {
      int rr = nh + nt * 16 + l15;
      bh[nt] = *(const bf16x8*)&Wsh[0][rr * 40 + quad * 8];
      bl[nt] = *(const bf16x8*)&Wsh[1][rr * 40 + quad * 8];
    }
    #pragma unroll
    for (int mt = 0; mt < 4; mt++)
      #pragma unroll
      for (int nt = 0; nt < 4; nt++) {
        acc[mt][nt] = __builtin_amdgcn_mfma_f32_16x16x32_bf16(ah[mt], bh[nt], acc[mt][nt], 0, 0, 0);
        acc[mt][nt] = __builtin_amdgcn_mfma_f32_16x16x32_bf16(ah[mt], bl[nt], acc[mt][nt], 0, 0, 0);
        acc[mt][nt] = __builtin_amdgcn_mfma_f32_16x16x32_bf16(al[mt], bh[nt], acc[mt][nt], 0, 0, 0);
      }
  }

  const float* biasd = bias + (size_t)d * bStride;
  float* Cd = C + (size_t)d * cStride;
  #pragma unroll
  for (int nt = 0; nt < 4; nt++) {
    int cn = n0 + nh + nt * 16 + l15;
    float bv = biasd[cn];
    #pragma unroll
    for (int mt = 0; mt < 4; mt++) {
      int mr = m0 + mh + mt * 16 + quad * 4;
      #pragma unroll
      for (int j = 0; j < 4; j++)
        Cd[(size_t)(mr + j) * N + cn] = acc[mt][nt][j] + bv;
    }
  }
}

// ---------------- split-bf16 MFMA LSTM, r13 structure + fixes ----------------
// 256 WGs: blockIdx = us*32 + isl; isl = d*16 + bg (8 slices of an island ==
// isl mod 8 -> one XCD under round-robin; heuristic only, protocol is
// placement-safe). Island = (d,bg): 8 slice-WGs, 4 batches.
// In-lane cell (r13): acc[mt][j] = gate j of unit us*32+w*8+quad (+4*mt),
// batch l15&3. Exchange word u32[batch][unit] = hh | hl<<16, sentinel-spin.
// Slab LDS swizzle: off(b, u) = b*512 + ((j<<3) ^ (((j>>4)&3)<<6) ^ ((b&1)<<6))
// + (u&3)*2, j = u>>2.  Double-buffered slab, one barrier per step.
__global__ __launch_bounds__(256, 1)
void k_lstm_mfma(const float* __restrict__ xg,
                 const u16* __restrict__ Whi, const u16* __restrict__ Wlo,
                 u16* __restrict__ houth, u16* __restrict__ houtl,
                 u32* __restrict__ hbx)
{
  __shared__ __align__(16) u16 hsh[2][1024];   // dbuf hi slabs (2KB each)
  __shared__ __align__(16) u16 hsl[2][1024];   // dbuf lo slabs

  int tid  = threadIdx.x;
  int us   = blockIdx.x >> 5;
  int isl  = blockIdx.x & 31;
  int d    = isl >> 4;
  int bg   = isl & 15;
  int lane = tid & 63;
  int w    = tid >> 6;
  int l15  = lane & 15;
  int quad = lane >> 4;
  int bpc  = l15 & 3;

  // A-frags: row = gate*256 + unit; gate = l15&3, unit = us*32+w*8+mt*4+(l15>>2)
  bf16x8 afh[2][8], afl[2][8];
  {
    size_t rowb = ((size_t)d * G4_ + (size_t)(l15 & 3) * 256
                   + us * 32 + w * 8 + (l15 >> 2)) * H_;
    const u16* WbH = Whi + rowb;
    const u16* WbL = Wlo + rowb;
    #pragma unroll
    for (int mt = 0; mt < 2; mt++)
      #pragma unroll
      for (int kt = 0; kt < 8; kt++) {
        afh[mt][kt] = *(const bf16x8*)(WbH + (size_t)mt * 4 * H_ + kt * 32 + quad * 8);
        afl[mt][kt] = *(const bf16x8*)(WbL + (size_t)mt * 4 * H_ + kt * 32 + quad * 8);
      }
  }
  #pragma unroll
  for (int mt = 0; mt < 2; mt++)
    #pragma unroll
    for (int kt = 0; kt < 8; kt++) {
      asm volatile("" : "+v"(afh[mt][kt]));
      asm volatile("" : "+v"(afl[mt][kt]));
    }

  float c0 = 0.f, c1 = 0.f;
  u32 pk0 = 0, pk1 = 0;

  // pull mapping: batch pb = wave id, 8B chunk pj = lane -> units pj*4..+3
  int pb = tid >> 6;
  int pj = tid & 63;
  bool mine = ((pj >> 3) == us);     // own slice self-populated from registers
  int wroff = pb * 512 + ((pj << 3) ^ (((pj >> 4) & 3) << 6) ^ ((pb & 1) << 6));

  // self-pop offsets: batch bpc, units u0c, u0c+4
  int u0c = us * 32 + w * 8 + quad;
  int js0 = us * 8 + w * 2;
  int soff0 = bpc * 512 + (((js0)     << 3) ^ ((((js0)     >> 4) & 3) << 6) ^ ((bpc & 1) << 6)) + quad * 2;
  int soff1 = bpc * 512 + (((js0 + 1) << 3) ^ ((((js0 + 1) >> 4) & 3) << 6) ^ ((bpc & 1) << 6)) + quad * 2;

  const float* xgd = xg + (size_t)d * S_ * B_ * G4_;
  u32* hb = hbx + (size_t)isl * S_ * 1024;

  for (int it = 0; it < S_; it++) {
    int s = d ? (S_ - 1 - it) : it;

    // acc init from unit-major xg (issued early; hides under the spin)
    f32x4 accA[2], accB[2];
    const float* xgrow = xgd + ((size_t)s * B_ + (bg * 4 + bpc)) * G4_ + (size_t)u0c * 4;
    accA[0] = *(const f32x4*)(xgrow);
    accA[1] = *(const f32x4*)(xgrow + 16);
    accB[0] = (f32x4)(0.f);
    accB[1] = (f32x4)(0.f);

    int p = (it - 1) & 1;            // slab parity holding step it-1 data
    if (it > 0) {
      if (!mine) {
        // hybrid spin: L2 fast path, agent fallback after 2 tries
        const u32* srcw = hb + (size_t)(it - 1) * 1024 + pb * 256 + pj * 4;
        u32x4 v = l2load128(srcw);
        int tries = 0;
        while ((v[0] == SENT32) | (v[1] == SENT32) | (v[2] == SENT32) | (v[3] == SENT32)) {
          if (++tries < 3) {
            v = l2load128(srcw);
          } else {
            __builtin_amdgcn_s_sleep(1);
            u64 a  = cload64((const u64*)srcw);
            u64 b2 = cload64((const u64*)srcw + 1);
            v[0] = (u32)a;  v[1] = (u32)(a >> 32);
            v[2] = (u32)b2; v[3] = (u32)(b2 >> 32);
          }
        }
        u64 hi64 = (u64)(v[0] & 0xFFFFu)         | ((u64)(v[1] & 0xFFFFu) << 16)
                 | ((u64)(v[2] & 0xFFFFu) << 32) | ((u64)(v[3] & 0xFFFFu) << 48);
        u64 lo64 = (u64)(v[0] >> 16)             | ((u64)(v[1] >> 16) << 16)
                 | ((u64)(v[2] >> 16) << 32)     | ((u64)(v[3] >> 16) << 48);
        *(u64*)((char*)hsh[p] + wroff) = hi64;
        *(u64*)((char*)hsl[p] + wroff) = lo64;
      }
      // self-populate own slice from previous step's registers
      if (l15 < 4) {
        *(u16*)((char*)hsh[p] + soff0) = (u16)pk0;
        *(u16*)((char*)hsl[p] + soff0) = (u16)(pk0 >> 16);
        *(u16*)((char*)hsh[p] + soff1) = (u16)pk1;
        *(u16*)((char*)hsl[p] + soff1) = (u16)(pk1 >> 16);
      }
      __syncthreads();   // single barrier per step (dbuf slab)

      #pragma unroll
      for (int kt = 0; kt < 8; kt++) {
        int j0 = (kt * 4 + quad) * 2;
        int coff = bpc * 512 + ((j0 << 3) ^ (((j0 >> 4) & 3) << 6) ^ ((bpc & 1) << 6));
        bf16x8 bh = *(const bf16x8*)((const char*)hsh[p] + coff);
        bf16x8 bl = *(const bf16x8*)((const char*)hsl[p] + coff);
        #pragma unroll
        for (int mt = 0; mt < 2; mt++) {
          accA[mt] = __builtin_amdgcn_mfma_f32_16x16x32_bf16(afh[mt][kt], bh, accA[mt], 0, 0, 0);
          accB[mt] = __builtin_amdgcn_mfma_f32_16x16x32_bf16(afh[mt][kt], bl, accB[mt], 0, 0, 0);
          accB[mt] = __builtin_amdgcn_mfma_f32_16x16x32_bf16(afl[mt][kt], bh, accB[mt], 0, 0, 0);
        }
      }
    }

    // in-lane cell: acc[mt][j] = gate j (i,f,g,o) of unit u0c + mt*4
    u32* hbrow = hb + (size_t)it * 1024 + bpc * 256 + u0c;
    {
      f32x4 g0 = accA[0] + accB[0];
      c0 = sigf(g0[1]) * c0 + sigf(g0[0]) * tanhf_(g0[2]);
      float h0 = sigf(g0[3]) * tanhf_(c0);
      u16 hh = f2bf(h0), hl = f2bf(h0 - bf2f(hh));
      pk0 = (u32)hh | ((u32)hl << 16);
      if (l15 < 4) cstore32(hbrow, pk0);           // publish ASAP
    }
    {
      f32x4 g1 = accA[1] + accB[1];
      c1 = sigf(g1[1]) * c1 + sigf(g1[0]) * tanhf_(g1[2]);
      float h1 = sigf(g1[3]) * tanhf_(c1);
      u16 hh = f2bf(h1), hl = f2bf(h1 - bf2f(hh));
      pk1 = (u32)hh | ((u32)hl << 16);
      if (l15 < 4) cstore32(hbrow + 4, pk1);
    }

    // hout: shfl-pack 8 consecutive units -> 2 x 16B stores by lanes < 4
    {
      u32 x1_0 = __shfl(pk0, l15 + 16), x1_1 = __shfl(pk1, l15 + 16);
      u32 x2_0 = __shfl(pk0, l15 + 32), x2_1 = __shfl(pk1, l15 + 32);
      u32 x3_0 = __shfl(pk0, l15 + 48), x3_1 = __shfl(pk1, l15 + 48);
      if (lane < 4) {
        u32x4 hivec, lovec;
        hivec[0] = (pk0 & 0xFFFFu)  | ((x1_0 & 0xFFFFu) << 16);
        hivec[1] = (x2_0 & 0xFFFFu) | ((x3_0 & 0xFFFFu) << 16);
        hivec[2] = (pk1 & 0xFFFFu)  | ((x1_1 & 0xFFFFu) << 16);
        hivec[3] = (x2_1 & 0xFFFFu) | ((x3_1 & 0xFFFFu) << 16);
        lovec[0] = (pk0 >> 16)  | (x1_0 & 0xFFFF0000u);
        lovec[1] = (x2_0 >> 16) | (x3_0 & 0xFFFF0000u);
        lovec[2] = (pk1 >> 16)  | (x1_1 & 0xFFFF0000u);
        lovec[3] = (x2_1 >> 16) | (x3_1 & 0xFFFF0000u);
        size_t ho = ((size_t)(bg * 4 + lane) * S_ + s) * D2H_ + d * H_ + us * 32 + w * 8;
        *(u32x4*)(houth + ho) = hivec;
        *(u32x4*)(houtl + ho) = lovec;
      }
    }
    // no end barrier: dbuf slab; next iter writes the other parity, and its
    // barrier orders 2-iteration-apart reuse (all threads must pass it).
  }
}

// ---------------- block reduction helpers ----------------
__device__ __forceinline__ float bsum(float v, float* sb) {
  int t = threadIdx.x;
  sb[t] = v; __syncthreads();
  for (int s = 128; s; s >>= 1) { if (t < s) sb[t] += sb[t + s]; __syncthreads(); }
  float r = sb[0]; __syncthreads(); return r;
}
__device__ __forceinline__ float bmax(float v, float* sb) {
  int t = threadIdx.x;
  sb[t] = v; __syncthreads();
  for (int s = 128; s; s >>= 1) { if (t < s) sb[t] = fmaxf(sb[t], sb[t + s]); __syncthreads(); }
  float r = sb[0]; __syncthreads(); return r;
}

// ---------------- pos branch ----------------
__global__ __launch_bounds__(256)
void k_pos(const float* __restrict__ pos, const float* __restrict__ fc1w, const float* __restrict__ fc1b,
           const float* __restrict__ fc2w, const float* __restrict__ fc2b,
           const float* __restrict__ lng, const float* __restrict__ lnb, float* __restrict__ pos_out)
{
  __shared__ float sp[256], sh[256], sb[256];
  int b = blockIdx.x, t = threadIdx.x;
  sp[t] = pos[b * 256 + t];
  __syncthreads();
  float a1 = fc1b[t];
  for (int s = 0; s < 256; s++) a1 += sp[s] * fc1w[s * 256 + t];
  a1 = fmaxf(a1, 0.f);
  sh[t] = a1; __syncthreads();
  float a2 = fc2b[t] + sp[t];
  for (int s = 0; s < 256; s++) a2 += sh[s] * fc2w[s * 256 + t];
  float m   = bsum(a2, sb) * (1.f / 256.f);
  float cen = a2 - m;
  float var = bsum(cen * cen, sb) * (1.f / 256.f);
  pos_out[b * 256 + t] = cen * rsqrtf(var + 1e-5f) * lng[t] + lnb[t];
}

// ---------------- CLN stage A ----------------
__global__ __launch_bounds__(256)
void k_clnA(const float* __restrict__ pos_out, const float* __restrict__ wd, const float* __restrict__ bd,
            const float* __restrict__ cw, const float* __restrict__ cb,
            float* __restrict__ wvec, float* __restrict__ bbvec)
{
  __shared__ float sp[256];
  int b = blockIdx.x, t = threadIdx.x;
  sp[t] = pos_out[b * 256 + t];
  __syncthreads();
  const float4* wdr = (const float4*)(wd + (size_t)t * 256);
  const float4* bdr = (const float4*)(bd + (size_t)t * 256);
  float aw = 0.f, ab = 0.f;
  for (int q = 0; q < 64; q++) {
    float4 w4 = wdr[q], b4 = bdr[q];
    float s0 = sp[q*4], s1 = sp[q*4+1], s2 = sp[q*4+2], s3 = sp[q*4+3];
    aw += s0*w4.x + s1*w4.y + s2*w4.z + s3*w4.w;
    ab += s0*b4.x + s1*b4.y + s2*b4.z + s3*b4.w;
  }
  wvec [b * 256 + t] = aw + cw[t];
  bbvec[b * 256 + t] = ab + cb[t];
}

// ---------------- CLN stage B + sentence dot ----------------
__global__ __launch_bounds__(256)
void k_clnB(const float* __restrict__ oc, const float* __restrict__ wvec, const float* __restrict__ bbvec,
            const float* __restrict__ alw, const float* __restrict__ alb,
            float* __restrict__ outn, float* __restrict__ sentence)
{
  __shared__ float sb[256];
  int bs = blockIdx.x, t = threadIdx.x;
  int b = bs >> 8;
  float v   = oc[(size_t)bs * 256 + t];
  float m   = bsum(v, sb) * (1.f / 256.f);
  float cen = v - m;
  float var = bsum(cen * cen, sb) * (1.f / 256.f);
  float o   = cen * rsqrtf(var + 1e-12f) * wvec[b * 256 + t] + bbvec[b * 256 + t];
  outn[(size_t)bs * 256 + t] = o;
  float sv = bsum(o * alw[t], sb);
  if (t == 0) sentence[bs] = sv + alb[0];
}

// ---------------- attention ----------------
__global__ __launch_bounds__(256)
void k_att(const float* __restrict__ sentence,
           const float* __restrict__ wq, const float* __restrict__ bq,
           const float* __restrict__ wk, const float* __restrict__ bk,
           const float* __restrict__ wv, const float* __restrict__ bv,
           const float* __restrict__ lng, const float* __restrict__ lnb,
           float* __restrict__ att)
{
  __shared__ float ss[256], sb[256];
  int b = blockIdx.x, t = threadIdx.x;
  ss[t] = sentence[b * 256 + t];
  __syncthreads();
  float q = bq[t], k = bk[t], vv = bv[t];
  for (int s = 0; s < 256; s++) {
    float sv = ss[s];
    q  += sv * wq[s * 256 + t];
    k  += sv * wk[s * 256 + t];
    vv += sv * wv[s * 256 + t];
  }
  float x  = q * k * (1.f / 16.f);
  float mx = bmax(x, sb);
  float e  = expf(x - mx);
  float sm = bsum(e, sb);
  float a  = (e / sm) * vv;
  float m   = bsum(a, sb) * (1.f / 256.f);
  float cen = a - m;
  float var = bsum(cen * cen, sb) * (1.f / 256.f);
  att[b * 256 + t] = cen * rsqrtf(var + 1e-5f) * lng[t] + lnb[t];
}

// ---------------- logits ----------------
__global__ __launch_bounds__(64)
void k_out(const float* __restrict__ outn, const float* __restrict__ att,
           const float* __restrict__ ow, const float* __restrict__ ob,
           float* __restrict__ logits)
{
  __shared__ float row[256];
  int bs = blockIdx.x, t = threadIdx.x;
  ((float4*)row)[t] = ((const float4*)(outn + (size_t)bs * 256))[t];
  __syncthreads();
  float a = att[bs];
  if (t < T_) {
    float acc = 0.f;
    for (int c = 0; c < 256; c++) acc += row[c] * ow[c * T_ + t];
    logits[(size_t)bs * T_ + t] = a * acc + ob[t];
  }
}

// ---------------- Viterbi ----------------
__global__ __launch_bounds__(64)
void k_viterbi(const float* __restrict__ logits, const float* __restrict__ start,
               const float* __restrict__ endv, const float* __restrict__ trans,
               float* __restrict__ tags)
{
  __shared__ float sc[16];
  __shared__ float str[169];
  __shared__ unsigned char hist[255 * 13];
  __shared__ int tg[256];
  int b = blockIdx.x, t = threadIdx.x;
  for (int i = t; i < 169; i += 64) str[i] = trans[i];
  if (t < 13) sc[t] = start[t] + logits[((size_t)b * 256) * 13 + t];
  __syncthreads();
  for (int s = 1; s < 256; s++) {
    float best = -1e30f; int bi = 0;
    if (t < 13) {
      best = sc[0] + str[t]; bi = 0;
      for (int i = 1; i < 13; i++) {
        float v = sc[i] + str[i * 13 + t];
        if (v > best) { best = v; bi = i; }
      }
    }
    __syncthreads();
    if (t < 13) {
      sc[t] = best + logits[((size_t)b * 256 + s) * 13 + t];
      hist[(s - 1) * 13 + t] = (unsigned char)bi;
    }
    __syncthreads();
  }
  if (t == 0) {
    float best = sc[0] + endv[0]; int last = 0;
    for (int j = 1; j < 13; j++) {
      float v = sc[j] + endv[j];
      if (v > best) { best = v; last = j; }
    }
    tg[255] = last;
    int cur = last;
    for (int s = 254; s >= 0; s--) { cur = hist[s * 13 + cur]; tg[s] = cur; }
  }
  __syncthreads();
  for (int s = t; s < 256; s += 64) tags[b * 256 + s] = (float)tg[s];
}

// ---------------- launch ----------------
extern "C" void kernel_launch(void* const* d_in, const int* in_sizes, int n_in,
                              void* d_out, int out_size, void* d_ws, size_t ws_size,
                              hipStream_t stream)
{
  const int*   x     = (const int*)  d_in[0];
  const float* pos   = (const float*)d_in[1];
  const float* emb   = (const float*)d_in[2];
  const float* Wih0  = (const float*)d_in[3];
  const float* Whh0  = (const float*)d_in[4];
  const float* b0    = (const float*)d_in[5];
  const float* Wih1  = (const float*)d_in[6];
  const float* Whh1  = (const float*)d_in[7];
  const float* b1    = (const float*)d_in[8];
  const float* fc1w  = (const float*)d_in[9];
  const float* fc1b  = (const float*)d_in[10];
  const float* fc2w  = (const float*)d_in[11];
  const float* fc2b  = (const float*)d_in[12];
  const float* plng  = (const float*)d_in[13];
  const float* plnb  = (const float*)d_in[14];
  const float* condw = (const float*)d_in[15];
  const float* condb = (const float*)d_in[16];
  const float* clnw  = (const float*)d_in[17];
  const float* clnb  = (const float*)d_in[18];
  const float* clnwd = (const float*)d_in[19];
  const float* clnbd = (const float*)d_in[20];
  const float* wq    = (const float*)d_in[21];
  const float* bq    = (const float*)d_in[22];
  const float* wk    = (const float*)d_in[23];
  const float* bk    = (const float*)d_in[24];
  const float* wv    = (const float*)d_in[25];
  const float* bv    = (const float*)d_in[26];
  const float* atlng = (const float*)d_in[27];
  const float* atlnb = (const float*)d_in[28];
  const float* alw   = (const float*)d_in[29];
  const float* alb   = (const float*)d_in[30];
  const float* ow    = (const float*)d_in[31];
  const float* ob    = (const float*)d_in[32];
  const float* cstart= (const float*)d_in[33];
  const float* cend  = (const float*)d_in[34];
  const float* ctrans= (const float*)d_in[35];

  const size_t BS = (size_t)B_ * S_;   // 16384
  float* ws = (float*)d_ws;
  float* r1   = ws;                    // embA hi/lo -> out_cond
  float* xg   = r1 + 5242880;          // fp32 pre-gates [2][S][B][unit*4+gate]
  float* l0r  = xg + 33554432;         // l0 hi/lo -> lstm1 exchange -> outn
  float* l1r  = l0r + 8388608;         // lstm0 exchange -> l1 hi/lo
  float* pos_out  = l1r + 8388608;
  float* wvec     = pos_out + 16384;
  float* bbvec    = wvec + 16384;
  float* sentence = bbvec + 16384;
  float* attv     = sentence + 16384;
  unsigned* flags = (unsigned*)(attv + 16384);     // (unused; layout kept)
  u16* whhh0 = (u16*)(flags + 65536);              // Whh splits: 4 x 524288 u16
  u16* whhl0 = whhh0 + 524288;
  u16* whhh1 = whhl0 + 524288;
  u16* whhl1 = whhh1 + 524288;
  u16* wih0h = whhl1 + 524288;                     // [2][1024][320] (row-permuted)
  u16* wih0l = wih0h + 655360;
  u16* wih1h = wih0l + 655360;                     // [2][1024][512] (row-permuted)
  u16* wih1l = wih1h + 1048576;
  u16* condTh = wih1l + 1048576;                   // [256][512]
  u16* condTl = condTh + 131072;
  float* b0p  = (float*)(condTl + 131072);         // permuted biases [2][1024]
  float* b1p  = b0p + 2048;

  u16* embh = (u16*)r1;
  u16* embl = embh + 5242880;
  float* out_cond = r1;
  u16* l0h = (u16*)l0r;
  u16* l0l = l0h + 8388608;
  u16* l1h = (u16*)l1r;
  u16* l1l = l1h + 8388608;
  u32* hb0 = (u32*)l1r;                 // lstm0 exchange (l1r free until lstm1 hout)
  u32* hb1 = (u32*)l0r;                 // lstm1 exchange (l0 consumed by bgemm1)
  const size_t HBBYTES = (size_t)32 * S_ * 1024 * sizeof(u32);  // 33,554,432 B
  float* outn = l0r;
  float* logits = (float*)d_out;
  float* tags   = logits + BS * T_;

  // sentinel-fill lstm0 exchange region (l1r untouched until lstm0)
  hipMemsetAsync(hb0, 0x7F, HBBYTES, stream);

  k_embed <<<dim3(B_ * S_), dim3(64), 0, stream>>>(x, emb, embh, embl);
  k_cvtbf2<<<dim3(2048), dim3(256), 0, stream>>>(Whh0, whhh0, whhl0, 2 * G4_ * H_);
  k_cvtbf2<<<dim3(2048), dim3(256), 0, stream>>>(Whh1, whhh1, whhl1, 2 * G4_ * H_);
  k_cvtpad<<<dim3(2048), dim3(256), 0, stream>>>(Wih0, wih0h, wih0l, 300, 320, 1);
  k_cvtpad<<<dim3(2048), dim3(256), 0, stream>>>(Wih1, wih1h, wih1l, 512, 512, 1);
  k_permb <<<dim3(8),    dim3(256), 0, stream>>>(b0, b0p);
  k_permb <<<dim3(8),    dim3(256), 0, stream>>>(b1, b1p);
  k_cvtT  <<<dim3(256),  dim3(256), 0, stream>>>(condw, condTh, condTl);

  // layer-0 pre-gates (unit-major via permuted W rows; coalesced epilogue)
  k_bgemm<<<dim3(8, 128, 2), dim3(256), 0, stream>>>(
      embh, embl, wih0h, wih0l, b0p, xg, 320, G4_, 1,
      (long)G4_ * 320, (long)G4_, (long)BS * G4_);
  k_lstm_mfma<<<dim3(256), dim3(256), 0, stream>>>(
      xg, whhh0, whhl0, l0h, l0l, hb0);

  // layer-1 pre-gates
  k_bgemm<<<dim3(8, 128, 2), dim3(256), 0, stream>>>(
      l0h, l0l, wih1h, wih1l, b1p, xg, 512, G4_, 1,
      (long)G4_ * 512, (long)G4_, (long)BS * G4_);
  // sentinel-fill lstm1 exchange region (l0h just consumed by the bgemm above)
  hipMemsetAsync(hb1, 0x7F, HBBYTES, stream);
  k_lstm_mfma<<<dim3(256), dim3(256), 0, stream>>>(
      xg, whhh1, whhl1, l1h, l1l, hb1);

  // cond projection (permute=0)
  k_bgemm<<<dim3(2, 128, 1), dim3(256), 0, stream>>>(
      l1h, l1l, condTh, condTl, condb, out_cond, 512, 256, 0, 0, 0, 0);

  k_pos <<<dim3(B_), dim3(256), 0, stream>>>(pos, fc1w, fc1b, fc2w, fc2b, plng, plnb, pos_out);
  k_clnA<<<dim3(B_), dim3(256), 0, stream>>>(pos_out, clnwd, clnbd, clnw, clnb, wvec, bbvec);
  k_clnB<<<dim3(B_ * S_), dim3(256), 0, stream>>>(out_cond, wvec, bbvec, alw, alb, outn, sentence);
  k_att <<<dim3(B_), dim3(256), 0, stream>>>(sentence, wq, bq, wk, bk, wv, bv, atlng, atlnb, attv);
  k_out <<<dim3(B_ * S_), dim3(64), 0, stream>>>(outn, attv, ow, ob, logits);
  k_viterbi<<<dim3(B_), dim3(64), 0, stream>>>(logits, cstart, cend, ctrans, tags);
}

// Round 8
// 1669.976 us; speedup vs baseline: 1.6253x; 1.1271x over previous
//
#include <hip/hip_runtime.h>
#include <math.h>

// BiLSTM-CRF, round 19: composed from verified-passing components only.
// r17/r18 post-mortem: the r12 gl-based lstm is RACY (1 pass / 2 fails of
// identical source; absmax 6.0 both fails). The r13-family in-lane lstm with
// explicit write->barrier->read->barrier hazard separation is 4/4 passing.
// This round: r13 lstm VERBATIM + r14's build-time W-row/bias permutation so
// the bgemm keeps its coalesced epilogue (removes r13's output-scatter cost).
// B=64 S=256 V=50000 E=300 H=256 T=13
#define B_    64
#define S_    256
#define E_    300
#define H_    256
#define T_    13
#define G4_   1024   // 4*H
#define D2H_  512    // 2*H

typedef short bf16x8 __attribute__((ext_vector_type(8)));   // 8 bf16 in 4 VGPRs
typedef float f32x4  __attribute__((ext_vector_type(4)));
typedef unsigned short u16;
typedef unsigned int   u32;
typedef unsigned long long u64;

#define SENT32 0x7F7F7F7Fu    // memset(0x7F) pattern; impossible packed-h dword

__device__ __forceinline__ float sigf(float x)   { return __builtin_amdgcn_rcpf(1.f + __expf(-x)); }
__device__ __forceinline__ float tanhf_(float x) { return __builtin_amdgcn_rcpf(1.f + __expf(-2.f*x))*2.f - 1.f; }

__device__ __forceinline__ u16 f2bf(float f) {
  union { float f; unsigned u; } v; v.f = f;
  unsigned r = v.u + 0x7fff + ((v.u >> 16) & 1);   // RNE
  return (u16)(r >> 16);
}
__device__ __forceinline__ float bf2f(u16 h) {
  union { unsigned u; float f; } v; v.u = ((unsigned)h) << 16;
  return v.f;
}

// coherent (agent-scope, relaxed) accessors
__device__ __forceinline__ u64 cload64(const u64* p) {
  return __hip_atomic_load(p, __ATOMIC_RELAXED, __HIP_MEMORY_SCOPE_AGENT);
}
__device__ __forceinline__ void cstore32(u32* p, u32 v) {
  __hip_atomic_store(p, v, __ATOMIC_RELAXED, __HIP_MEMORY_SCOPE_AGENT);
}

// ---------------- embedding gather -> bf16 hi/lo, K padded 300->320 ----------------
__global__ __launch_bounds__(64)
void k_embed(const int* __restrict__ x, const float* __restrict__ emb,
             u16* __restrict__ oh, u16* __restrict__ ol) {
  int bs = blockIdx.x;
  int xv = x[bs];
  const float4* src = (const float4*)(emb + (size_t)xv * E_);
  u64* dh = (u64*)(oh + (size_t)bs * 320);
  u64* dl = (u64*)(ol + (size_t)bs * 320);
  for (int q = threadIdx.x; q < 80; q += 64) {
    float4 v = (q < 75) ? src[q] : make_float4(0.f, 0.f, 0.f, 0.f);
    u16 hh[4], ll[4];
    float vv[4] = {v.x, v.y, v.z, v.w};
    #pragma unroll
    for (int j = 0; j < 4; j++) {
      hh[j] = f2bf(vv[j]);
      ll[j] = f2bf(vv[j] - bf2f(hh[j]));
    }
    dh[q] = (u64)hh[0] | ((u64)hh[1] << 16) | ((u64)hh[2] << 32) | ((u64)hh[3] << 48);
    dl[q] = (u64)ll[0] | ((u64)ll[1] << 16) | ((u64)ll[2] << 32) | ((u64)ll[3] << 48);
  }
}

// ---------------- fp32 -> bf16 hi/lo split (flat) ----------------
__global__ __launch_bounds__(256)
void k_cvtbf2(const float* __restrict__ w, u16* __restrict__ hi, u16* __restrict__ lo, int n) {
  int i = blockIdx.x * 256 + threadIdx.x;
  if (i < n) {
    float v = w[i];
    u16 h = f2bf(v);
    hi[i] = h;
    lo[i] = f2bf(v - bf2f(h));
  }
}

// ---------------- fp32 -> bf16 hi/lo, K padding, optional row permute -------------
// perm=1: source row (d, gate*256+unit) lands at buffer row (d, unit*4+gate),
// so the GEMM's output columns come out unit-major with a COALESCED epilogue.
__global__ __launch_bounds__(256)
void k_cvtpad(const float* __restrict__ w, u16* __restrict__ hi, u16* __restrict__ lo,
              int Ksrc, int Kpad, int perm) {
  int r = blockIdx.x;
  int rl = r & 1023, dd = r >> 10;
  int ro = perm ? ((dd << 10) | ((rl & 255) << 2) | (rl >> 8)) : r;
  for (int k = threadIdx.x; k < Kpad; k += 256) {
    float v = (k < Ksrc) ? w[(size_t)r * Ksrc + k] : 0.f;
    u16 h = f2bf(v);
    hi[(size_t)ro * Kpad + k] = h;
    lo[(size_t)ro * Kpad + k] = f2bf(v - bf2f(h));
  }
}

// ---------------- bias permute: (d, gate*256+unit) -> (d, unit*4+gate) ------------
__global__ __launch_bounds__(256)
void k_permb(const float* __restrict__ b, float* __restrict__ bp) {
  int i = blockIdx.x * 256 + threadIdx.x;      // 0..2047
  int rl = i & 1023, dd = i >> 10;
  bp[(dd << 10) | ((rl & 255) << 2) | (rl >> 8)] = b[i];
}

// ---------------- cond_w (512,256) -> transposed hi/lo (256,512) ----------------
__global__ __launch_bounds__(256)
void k_cvtT(const float* __restrict__ w, u16* __restrict__ hi, u16* __restrict__ lo) {
  int n = blockIdx.x;
  for (int k = threadIdx.x; k < 512; k += 256) {
    float v = w[(size_t)k * 256 + n];
    u16 h = f2bf(v);
    hi[(size_t)n * 512 + k] = h;
    lo[(size_t)n * 512 + k] = f2bf(v - bf2f(h));
  }
}

// ---------------- split-bf16 MFMA GEMM: C = A @ W^T + bias (coalesced epilogue) ---
__global__ __launch_bounds__(256)
void k_bgemm(const u16* __restrict__ Ahi, const u16* __restrict__ Alo,
             const u16* __restrict__ Whi, const u16* __restrict__ Wlo,
             const float* __restrict__ bias, float* __restrict__ C,
             int K, int N, int permute, long wStride, long bStride, long cStride)
{
  __shared__ u16 Ash[2][128 * 40];
  __shared__ u16 Wsh[2][128 * 40];

  int tid = threadIdx.x;
  int d   = blockIdx.z;
  int n0  = blockIdx.x * 128, m0 = blockIdx.y * 128;
  int lane = tid & 63;
  int w    = tid >> 6;
  int l15  = lane & 15;
  int quad = lane >> 4;
  int mh = (w >> 1) * 64, nh = (w & 1) * 64;

  int comp = tid >> 7, row = tid & 127;
  int gr = m0 + row;
  int ar = permute ? ((gr & 63) * S_ + (gr >> 6)) : gr;
  const u16* Asrc = (comp ? Alo : Ahi) + (size_t)ar * K;
  const u16* Wsrc = (comp ? Wlo : Whi) + (size_t)d * wStride + (size_t)(n0 + row) * K;
  u16* AshC = &Ash[comp][row * 40];
  u16* WshC = &Wsh[comp][row * 40];

  f32x4 acc[4][4];
  #pragma unroll
  for (int mt = 0; mt < 4; mt++)
    #pragma unroll
    for (int nt = 0; nt < 4; nt++) acc[mt][nt] = (f32x4)(0.f);

  for (int k0 = 0; k0 < K; k0 += 32) {
    float4 a0 = *(const float4*)(Asrc + k0);
    float4 a1 = *(const float4*)(Asrc + k0 + 8);
    float4 a2 = *(const float4*)(Asrc + k0 + 16);
    float4 a3 = *(const float4*)(Asrc + k0 + 24);
    float4 w0 = *(const float4*)(Wsrc + k0);
    float4 w1 = *(const float4*)(Wsrc + k0 + 8);
    float4 w2 = *(const float4*)(Wsrc + k0 + 16);
    float4 w3 = *(const float4*)(Wsrc + k0 + 24);
    __syncthreads();
    *(float4*)(AshC)      = a0; *(float4*)(AshC + 8)  = a1;
    *(float4*)(AshC + 16) = a2; *(float4*)(AshC + 24) = a3;
    *(float4*)(WshC)      = w0; *(float4*)(WshC + 8)  = w1;
    *(float4*)(WshC + 16) = w2; *(float4*)(WshC + 24) = w3;
    __syncthreads();

    bf16x8 ah[4], al[4], bh[4], bl[4];
    #pragma unroll
    for (int mt = 0; mt < 4; mt++) {
      int rr = mh + mt * 16 + l15;
      ah[mt] = *(const bf16x8*)&Ash[0][rr * 40 + quad * 8];
      al[mt] = *(const bf16x8*)&Ash[1][rr * 40 + quad * 8];
    }
    #pragma unroll
    for (int nt = 0; nt < 4; nt++) {
      int rr = nh + nt * 16 + l15;
      bh[nt] = *(const bf16x8*)&Wsh[0][rr * 40 + quad * 8];
      bl[nt] = *(const bf16x8*)&Wsh[1][rr * 40 + quad * 8];
    }
    #pragma unroll
    for (int mt = 0; mt < 4; mt++)
      #pragma unroll
      for (int nt = 0; nt < 4; nt++) {
        acc[mt][nt] = __builtin_amdgcn_mfma_f32_16x16x32_bf16(ah[mt], bh[nt], acc[mt][nt], 0, 0, 0);
        acc[mt][nt] = __builtin_amdgcn_mfma_f32_16x16x32_bf16(ah[mt], bl[nt], acc[mt][nt], 0, 0, 0);
        acc[mt][nt] = __builtin_amdgcn_mfma_f32_16x16x32_bf16(al[mt], bh[nt], acc[mt][nt], 0, 0, 0);
      }
  }

  const float* biasd = bias + (size_t)d * bStride;
  float* Cd = C + (size_t)d * cStride;
  #pragma unroll
  for (int nt = 0; nt < 4; nt++) {
    int cn = n0 + nh + nt * 16 + l15;
    float bv = biasd[cn];
    #pragma unroll
    for (int mt = 0; mt < 4; mt++) {
      int mr = m0 + mh + mt * 16 + quad * 4;
      #pragma unroll
      for (int j = 0; j < 4; j++)
        Cd[(size_t)(mr + j) * N + cn] = acc[mt][nt][j] + bv;
    }
  }
}

// ---------------- split-bf16 MFMA LSTM, 4-batch islands, in-lane cell (r13) -------
// VERBATIM r13 kernel (passed, 500us/dispatch). 256 WGs: blockIdx.x =
// d*128 + bg*8 + us. Island = (d,bg): 8 slice-WGs, 4 batches.
// A-rows: m = unit_sub*4 + gate  =>  acc[mt][j] = gate-j pregate for unit
// us*32 + wave*8 + mt*4 + quad, batch l15&3. Cell update fully in-lane.
// Exchange slab per (island, step): u32[bc 0..3][unit 0..255], word = hh|hl<<16.
// Sentinel-spin (memset 0x7F; stored word can never be 0x7F7F7F7F; all 4
// dword halves checked). Slab hazard discipline: all LDS slab writes
// (pull-unpack + register self-pop) happen between the spin and barrier#1;
// slab reads happen between barrier#1 and barrier#2 (end of iteration).
__global__ __launch_bounds__(256, 1)
void k_lstm_mfma(const float* __restrict__ xg,
                 const u16* __restrict__ Whi, const u16* __restrict__ Wlo,
                 u16* __restrict__ houth, u16* __restrict__ houtl,
                 u32* __restrict__ hbx)
{
  __shared__ __align__(16) u16 hsh[4 * 256];         // 2 KB hi slab
  __shared__ __align__(16) u16 hsl[4 * 256];         // 2 KB lo slab

  int tid  = threadIdx.x;
  int us   = blockIdx.x & 7;
  int bg   = (blockIdx.x >> 3) & 15;
  int d    = blockIdx.x >> 7;
  int lane = tid & 63;
  int w    = tid >> 6;
  int l15  = lane & 15;
  int quad = lane >> 4;
  int bpc  = l15 & 3;                 // real batch column (cols 4-15 alias/discard)

  // A-frags: row = (l15&3)*256 + us*32 + w*8 + mt*4 + (l15>>2)  (gate = l15&3)
  bf16x8 afh[2][8], afl[2][8];
  {
    const u16* WbH = Whi + ((size_t)d * G4_ + (size_t)(l15 & 3) * 256
                            + us * 32 + w * 8 + (l15 >> 2)) * H_;
    const u16* WbL = Wlo + ((size_t)d * G4_ + (size_t)(l15 & 3) * 256
                            + us * 32 + w * 8 + (l15 >> 2)) * H_;
    #pragma unroll
    for (int mt = 0; mt < 2; mt++)
      #pragma unroll
      for (int kt = 0; kt < 8; kt++) {
        afh[mt][kt] = *(const bf16x8*)(WbH + (size_t)mt * 4 * H_ + kt * 32 + quad * 8);
        afl[mt][kt] = *(const bf16x8*)(WbL + (size_t)mt * 4 * H_ + kt * 32 + quad * 8);
      }
  }

  float c0 = 0.f, c1 = 0.f;
  u32 pk0 = 0, pk1 = 0;               // packed h (hi|lo<<16) from previous step

  // pull mapping: thread owns 4 slab words [pb][pu0..pu0+3]
  int pb  = tid >> 6;
  int pu0 = (tid & 63) << 2;
  bool mine = (pu0 >> 5) == us;       // own slice self-populated from registers
  int pwoff = ((pb * 256 + pu0) * 2) ^ ((pb & 1) << 6);   // LDS byte, 8B-aligned

  // cell/self-pop constants: units u0c (mt=0), u0c+4 (mt=1), batch bpc
  int u0c   = us * 32 + w * 8 + quad;
  int soff0 = ((bpc * 256 + u0c) * 2)     ^ ((bpc & 1) << 6);
  int soff1 = ((bpc * 256 + u0c + 4) * 2) ^ ((bpc & 1) << 6);

  const float* xgd = xg + (size_t)d * S_ * B_ * G4_;
  u32* hb = hbx + (size_t)(d * 16 + bg) * S_ * 1024;

  for (int it = 0; it < S_; it++) {
    int s = d ? (S_ - 1 - it) : it;

    // acc init from unit-major xg (issued early; latency hides under the poll)
    f32x4 accA[2], accB[2];
    const float* xgrow = xgd + ((size_t)s * B_ + (bg * 4 + bpc)) * G4_
                       + (size_t)(us * 32 + w * 8 + quad) * 4;
    accA[0] = *(const f32x4*)(xgrow);
    accA[1] = *(const f32x4*)(xgrow + 16);
    accB[0] = (f32x4)(0.f);
    accB[1] = (f32x4)(0.f);

    if (it > 0) {
      // phase 2a: remote pull (spin on the data words themselves)
      if (!mine) {
        const u64* src = (const u64*)(hb + (size_t)(it - 1) * 1024 + pb * 256 + pu0);
        u64 a = cload64(src), b2 = cload64(src + 1);
        while (((u32)a == SENT32) | ((u32)(a >> 32) == SENT32) |
               ((u32)b2 == SENT32) | ((u32)(b2 >> 32) == SENT32)) {
          __builtin_amdgcn_s_sleep(1);
          a = cload64(src); b2 = cload64(src + 1);
        }
        u64 hi64 = (a & 0xFFFFull) | (((a >> 32) & 0xFFFFull) << 16)
                 | ((b2 & 0xFFFFull) << 32) | (((b2 >> 32) & 0xFFFFull) << 48);
        u64 lo64 = ((a >> 16) & 0xFFFFull) | (((a >> 48) & 0xFFFFull) << 16)
                 | (((b2 >> 16) & 0xFFFFull) << 32) | ((b2 >> 48) << 48);
        *(u64*)((char*)hsh + pwoff) = hi64;
        *(u64*)((char*)hsl + pwoff) = lo64;
      }
      // phase 2b: self-populate own slice from previous step's registers
      if (l15 < 4) {
        *(u16*)((char*)hsh + soff0) = (u16)pk0;
        *(u16*)((char*)hsl + soff0) = (u16)(pk0 >> 16);
        *(u16*)((char*)hsh + soff1) = (u16)pk1;
        *(u16*)((char*)hsl + soff1) = (u16)(pk1 >> 16);
      }
      __syncthreads();   // barrier#1: slab(it-1) complete

      #pragma unroll
      for (int kt = 0; kt < 8; kt++) {
        int coff = ((bpc * 256 + (kt * 4 + quad) * 8) * 2) ^ ((bpc & 1) << 6);
        bf16x8 bh = *(const bf16x8*)((const char*)hsh + coff);
        bf16x8 bl = *(const bf16x8*)((const char*)hsl + coff);
        #pragma unroll
        for (int mt = 0; mt < 2; mt++) {
          accA[mt] = __builtin_amdgcn_mfma_f32_16x16x32_bf16(afh[mt][kt], bh, accA[mt], 0, 0, 0);
          accB[mt] = __builtin_amdgcn_mfma_f32_16x16x32_bf16(afh[mt][kt], bl, accB[mt], 0, 0, 0);
          accB[mt] = __builtin_amdgcn_mfma_f32_16x16x32_bf16(afl[mt][kt], bh, accB[mt], 0, 0, 0);
        }
      }
    }

    // in-lane cell update: acc[mt][j] = gate j (i,f,g,o) of unit u0c + mt*4
    u32* hbrow = hb + (size_t)it * 1024 + bpc * 256 + u0c;
    {
      f32x4 g0 = accA[0] + accB[0];
      c0 = sigf(g0[1]) * c0 + sigf(g0[0]) * tanhf_(g0[2]);
      float h0 = sigf(g0[3]) * tanhf_(c0);
      u16 hh = f2bf(h0), hl = f2bf(h0 - bf2f(hh));
      pk0 = (u32)hh | ((u32)hl << 16);
      if (l15 < 4) cstore32(hbrow, pk0);           // exchange ASAP
    }
    {
      f32x4 g1 = accA[1] + accB[1];
      c1 = sigf(g1[1]) * c1 + sigf(g1[0]) * tanhf_(g1[2]);
      float h1 = sigf(g1[3]) * tanhf_(c1);
      u16 hh = f2bf(h1), hl = f2bf(h1 - bf2f(hh));
      pk1 = (u32)hh | ((u32)hl << 16);
      if (l15 < 4) cstore32(hbrow + 4, pk1);
    }

    // layer output (off critical path)
    if (l15 < 4) {
      size_t ho = ((size_t)(bg * 4 + bpc) * S_ + s) * D2H_ + d * H_ + u0c;
      houth[ho]     = (u16)pk0;
      houtl[ho]     = (u16)(pk0 >> 16);
      houth[ho + 4] = (u16)pk1;
      houtl[ho + 4] = (u16)(pk1 >> 16);
    }

    __syncthreads();   // barrier#2: drain slab reads before next iter's writes
  }
}

// ---------------- block reduction helpers ----------------
__device__ __forceinline__ float bsum(float v, float* sb) {
  int t = threadIdx.x;
  sb[t] = v; __syncthreads();
  for (int s = 128; s; s >>= 1) { if (t < s) sb[t] += sb[t + s]; __syncthreads(); }
  float r = sb[0]; __syncthreads(); return r;
}
__device__ __forceinline__ float bmax(float v, float* sb) {
  int t = threadIdx.x;
  sb[t] = v; __syncthreads();
  for (int s = 128; s; s >>= 1) { if (t < s) sb[t] = fmaxf(sb[t], sb[t + s]); __syncthreads(); }
  float r = sb[0]; __syncthreads(); return r;
}

// ---------------- pos branch ----------------
__global__ __launch_bounds__(256)
void k_pos(const float* __restrict__ pos, const float* __restrict__ fc1w, const float* __restrict__ fc1b,
           const float* __restrict__ fc2w, const float* __restrict__ fc2b,
           const float* __restrict__ lng, const float* __restrict__ lnb, float* __restrict__ pos_out)
{
  __shared__ float sp[256], sh[256], sb[256];
  int b = blockIdx.x, t = threadIdx.x;
  sp[t] = pos[b * 256 + t];
  __syncthreads();
  float a1 = fc1b[t];
  for (int s = 0; s < 256; s++) a1 += sp[s] * fc1w[s * 256 + t];
  a1 = fmaxf(a1, 0.f);
  sh[t] = a1; __syncthreads();
  float a2 = fc2b[t] + sp[t];
  for (int s = 0; s < 256; s++) a2 += sh[s] * fc2w[s * 256 + t];
  float m   = bsum(a2, sb) * (1.f / 256.f);
  float cen = a2 - m;
  float var = bsum(cen * cen, sb) * (1.f / 256.f);
  pos_out[b * 256 + t] = cen * rsqrtf(var + 1e-5f) * lng[t] + lnb[t];
}

// ---------------- CLN stage A ----------------
__global__ __launch_bounds__(256)
void k_clnA(const float* __restrict__ pos_out, const float* __restrict__ wd, const float* __restrict__ bd,
            const float* __restrict__ cw, const float* __restrict__ cb,
            float* __restrict__ wvec, float* __restrict__ bbvec)
{
  __shared__ float sp[256];
  int b = blockIdx.x, t = threadIdx.x;
  sp[t] = pos_out[b * 256 + t];
  __syncthreads();
  const float4* wdr = (const float4*)(wd + (size_t)t * 256);
  const float4* bdr = (const float4*)(bd + (size_t)t * 256);
  float aw = 0.f, ab = 0.f;
  for (int q = 0; q < 64; q++) {
    float4 w4 = wdr[q], b4 = bdr[q];
    float s0 = sp[q*4], s1 = sp[q*4+1], s2 = sp[q*4+2], s3 = sp[q*4+3];
    aw += s0*w4.x + s1*w4.y + s2*w4.z + s3*w4.w;
    ab += s0*b4.x + s1*b4.y + s2*b4.z + s3*b4.w;
  }
  wvec [b * 256 + t] = aw + cw[t];
  bbvec[b * 256 + t] = ab + cb[t];
}

// ---------------- CLN stage B + sentence dot ----------------
__global__ __launch_bounds__(256)
void k_clnB(const float* __restrict__ oc, const float* __restrict__ wvec, const float* __restrict__ bbvec,
            const float* __restrict__ alw, const float* __restrict__ alb,
            float* __restrict__ outn, float* __restrict__ sentence)
{
  __shared__ float sb[256];
  int bs = blockIdx.x, t = threadIdx.x;
  int b = bs >> 8;
  float v   = oc[(size_t)bs * 256 + t];
  float m   = bsum(v, sb) * (1.f / 256.f);
  float cen = v - m;
  float var = bsum(cen * cen, sb) * (1.f / 256.f);
  float o   = cen * rsqrtf(var + 1e-12f) * wvec[b * 256 + t] + bbvec[b * 256 + t];
  outn[(size_t)bs * 256 + t] = o;
  float sv = bsum(o * alw[t], sb);
  if (t == 0) sentence[bs] = sv + alb[0];
}

// ---------------- attention ----------------
__global__ __launch_bounds__(256)
void k_att(const float* __restrict__ sentence,
           const float* __restrict__ wq, const float* __restrict__ bq,
           const float* __restrict__ wk, const float* __restrict__ bk,
           const float* __restrict__ wv, const float* __restrict__ bv,
           const float* __restrict__ lng, const float* __restrict__ lnb,
           float* __restrict__ att)
{
  __shared__ float ss[256], sb[256];
  int b = blockIdx.x, t = threadIdx.x;
  ss[t] = sentence[b * 256 + t];
  __syncthreads();
  float q = bq[t], k = bk[t], vv = bv[t];
  for (int s = 0; s < 256; s++) {
    float sv = ss[s];
    q  += sv * wq[s * 256 + t];
    k  += sv * wk[s * 256 + t];
    vv += sv * wv[s * 256 + t];
  }
  float x  = q * k * (1.f / 16.f);
  float mx = bmax(x, sb);
  float e  = expf(x - mx);
  float sm = bsum(e, sb);
  float a  = (e / sm) * vv;
  float m   = bsum(a, sb) * (1.f / 256.f);
  float cen = a - m;
  float var = bsum(cen * cen, sb) * (1.f / 256.f);
  att[b * 256 + t] = cen * rsqrtf(var + 1e-5f) * lng[t] + lnb[t];
}

// ---------------- logits ----------------
__global__ __launch_bounds__(64)
void k_out(const float* __restrict__ outn, const float* __restrict__ att,
           const float* __restrict__ ow, const float* __restrict__ ob,
           float* __restrict__ logits)
{
  __shared__ float row[256];
  int bs = blockIdx.x, t = threadIdx.x;
  ((float4*)row)[t] = ((const float4*)(outn + (size_t)bs * 256))[t];
  __syncthreads();
  float a = att[bs];
  if (t < T_) {
    float acc = 0.f;
    for (int c = 0; c < 256; c++) acc += row[c] * ow[c * T_ + t];
    logits[(size_t)bs * T_ + t] = a * acc + ob[t];
  }
}

// ---------------- Viterbi ----------------
__global__ __launch_bounds__(64)
void k_viterbi(const float* __restrict__ logits, const float* __restrict__ start,
               const float* __restrict__ endv, const float* __restrict__ trans,
               float* __restrict__ tags)
{
  __shared__ float sc[16];
  __shared__ float str[169];
  __shared__ unsigned char hist[255 * 13];
  __shared__ int tg[256];
  int b = blockIdx.x, t = threadIdx.x;
  for (int i = t; i < 169; i += 64) str[i] = trans[i];
  if (t < 13) sc[t] = start[t] + logits[((size_t)b * 256) * 13 + t];
  __syncthreads();
  for (int s = 1; s < 256; s++) {
    float best = -1e30f; int bi = 0;
    if (t < 13) {
      best = sc[0] + str[t]; bi = 0;
      for (int i = 1; i < 13; i++) {
        float v = sc[i] + str[i * 13 + t];
        if (v > best) { best = v; bi = i; }
      }
    }
    __syncthreads();
    if (t < 13) {
      sc[t] = best + logits[((size_t)b * 256 + s) * 13 + t];
      hist[(s - 1) * 13 + t] = (unsigned char)bi;
    }
    __syncthreads();
  }
  if (t == 0) {
    float best = sc[0] + endv[0]; int last = 0;
    for (int j = 1; j < 13; j++) {
      float v = sc[j] + endv[j];
      if (v > best) { best = v; last = j; }
    }
    tg[255] = last;
    int cur = last;
    for (int s = 254; s >= 0; s--) { cur = hist[s * 13 + cur]; tg[s] = cur; }
  }
  __syncthreads();
  for (int s = t; s < 256; s += 64) tags[b * 256 + s] = (float)tg[s];
}

// ---------------- launch ----------------
extern "C" void kernel_launch(void* const* d_in, const int* in_sizes, int n_in,
                              void* d_out, int out_size, void* d_ws, size_t ws_size,
                              hipStream_t stream)
{
  const int*   x     = (const int*)  d_in[0];
  const float* pos   = (const float*)d_in[1];
  const float* emb   = (const float*)d_in[2];
  const float* Wih0  = (const float*)d_in[3];
  const float* Whh0  = (const float*)d_in[4];
  const float* b0    = (const float*)d_in[5];
  const float* Wih1  = (const float*)d_in[6];
  const float* Whh1  = (const float*)d_in[7];
  const float* b1    = (const float*)d_in[8];
  const float* fc1w  = (const float*)d_in[9];
  const float* fc1b  = (const float*)d_in[10];
  const float* fc2w  = (const float*)d_in[11];
  const float* fc2b  = (const float*)d_in[12];
  const float* plng  = (const float*)d_in[13];
  const float* plnb  = (const float*)d_in[14];
  const float* condw = (const float*)d_in[15];
  const float* condb = (const float*)d_in[16];
  const float* clnw  = (const float*)d_in[17];
  const float* clnb  = (const float*)d_in[18];
  const float* clnwd = (const float*)d_in[19];
  const float* clnbd = (const float*)d_in[20];
  const float* wq    = (const float*)d_in[21];
  const float* bq    = (const float*)d_in[22];
  const float* wk    = (const float*)d_in[23];
  const float* bk    = (const float*)d_in[24];
  const float* wv    = (const float*)d_in[25];
  const float* bv    = (const float*)d_in[26];
  const float* atlng = (const float*)d_in[27];
  const float* atlnb = (const float*)d_in[28];
  const float* alw   = (const float*)d_in[29];
  const float* alb   = (const float*)d_in[30];
  const float* ow    = (const float*)d_in[31];
  const float* ob    = (const float*)d_in[32];
  const float* cstart= (const float*)d_in[33];
  const float* cend  = (const float*)d_in[34];
  const float* ctrans= (const float*)d_in[35];

  const size_t BS = (size_t)B_ * S_;   // 16384
  float* ws = (float*)d_ws;
  float* r1   = ws;                    // embA hi/lo -> out_cond
  float* xg   = r1 + 5242880;          // fp32 pre-gates [2][S][B][unit*4+gate]
  float* l0r  = xg + 33554432;         // l0 hi/lo -> lstm1 exchange -> outn
  float* l1r  = l0r + 8388608;         // lstm0 exchange -> l1 hi/lo
  float* pos_out  = l1r + 8388608;
  float* wvec     = pos_out + 16384;
  float* bbvec    = wvec + 16384;
  float* sentence = bbvec + 16384;
  float* attv     = sentence + 16384;
  unsigned* flags = (unsigned*)(attv + 16384);     // (unused; layout kept)
  u16* whhh0 = (u16*)(flags + 65536);              // Whh splits: 4 x 524288 u16
  u16* whhl0 = whhh0 + 524288;
  u16* whhh1 = whhl0 + 524288;
  u16* whhl1 = whhh1 + 524288;
  u16* wih0h = whhl1 + 524288;                     // [2][1024][320] (row-permuted)
  u16* wih0l = wih0h + 655360;
  u16* wih1h = wih0l + 655360;                     // [2][1024][512] (row-permuted)
  u16* wih1l = wih1h + 1048576;
  u16* condTh = wih1l + 1048576;                   // [256][512]
  u16* condTl = condTh + 131072;
  float* b0p  = (float*)(condTl + 131072);         // permuted biases [2][1024]
  float* b1p  = b0p + 2048;

  u16* embh = (u16*)r1;
  u16* embl = embh + 5242880;
  float* out_cond = r1;
  u16* l0h = (u16*)l0r;
  u16* l0l = l0h + 8388608;
  u16* l1h = (u16*)l1r;
  u16* l1l = l1h + 8388608;
  u32* hb0 = (u32*)l1r;                 // lstm0 exchange (l1r free until lstm1 hout)
  u32* hb1 = (u32*)l0r;                 // lstm1 exchange (l0 consumed by bgemm1)
  const size_t HBBYTES = (size_t)32 * S_ * 1024 * sizeof(u32);  // 33,554,432 B
  float* outn = l0r;
  float* logits = (float*)d_out;
  float* tags   = logits + BS * T_;

  // sentinel-fill lstm0 exchange region (l1r untouched until lstm0)
  hipMemsetAsync(hb0, 0x7F, HBBYTES, stream);

  k_embed <<<dim3(B_ * S_), dim3(64), 0, stream>>>(x, emb, embh, embl);
  k_cvtbf2<<<dim3(2048), dim3(256), 0, stream>>>(Whh0, whhh0, whhl0, 2 * G4_ * H_);
  k_cvtbf2<<<dim3(2048), dim3(256), 0, stream>>>(Whh1, whhh1, whhl1, 2 * G4_ * H_);
  k_cvtpad<<<dim3(2048), dim3(256), 0, stream>>>(Wih0, wih0h, wih0l, 300, 320, 1);
  k_cvtpad<<<dim3(2048), dim3(256), 0, stream>>>(Wih1, wih1h, wih1l, 512, 512, 1);
  k_permb <<<dim3(8),    dim3(256), 0, stream>>>(b0, b0p);
  k_permb <<<dim3(8),    dim3(256), 0, stream>>>(b1, b1p);
  k_cvtT  <<<dim3(256),  dim3(256), 0, stream>>>(condw, condTh, condTl);

  // layer-0 pre-gates (unit-major via permuted W rows; coalesced epilogue)
  k_bgemm<<<dim3(8, 128, 2), dim3(256), 0, stream>>>(
      embh, embl, wih0h, wih0l, b0p, xg, 320, G4_, 1,
      (long)G4_ * 320, (long)G4_, (long)BS * G4_);
  k_lstm_mfma<<<dim3(256), dim3(256), 0, stream>>>(
      xg, whhh0, whhl0, l0h, l0l, hb0);

  // layer-1 pre-gates
  k_bgemm<<<dim3(8, 128, 2), dim3(256), 0, stream>>>(
      l0h, l0l, wih1h, wih1l, b1p, xg, 512, G4_, 1,
      (long)G4_ * 512, (long)G4_, (long)BS * G4_);
  // sentinel-fill lstm1 exchange region (l0h just consumed by the bgemm above)
  hipMemsetAsync(hb1, 0x7F, HBBYTES, stream);
  k_lstm_mfma<<<dim3(256), dim3(256), 0, stream>>>(
      xg, whhh1, whhl1, l1h, l1l, hb1);

  // cond projection (permute=0: no remap anywhere)
  k_bgemm<<<dim3(2, 128, 1), dim3(256), 0, stream>>>(
      l1h, l1l, condTh, condTl, condb, out_cond, 512, 256, 0, 0, 0, 0);

  k_pos <<<dim3(B_), dim3(256), 0, stream>>>(pos, fc1w, fc1b, fc2w, fc2b, plng, plnb, pos_out);
  k_clnA<<<dim3(B_), dim3(256), 0, stream>>>(pos_out, clnwd, clnbd, clnw, clnb, wvec, bbvec);
  k_clnB<<<dim3(B_ * S_), dim3(256), 0, stream>>>(out_cond, wvec, bbvec, alw, alb, outn, sentence);
  k_att <<<dim3(B_), dim3(256), 0, stream>>>(sentence, wq, bq, wk, bk, wv, bv, atlng, atlnb, attv);
  k_out <<<dim3(B_ * S_), dim3(64), 0, stream>>>(outn, attv, ow, ob, logits);
  k_viterbi<<<dim3(B_), dim3(64), 0, stream>>>(logits, cstart, cend, ctrans, tags);
}

// Round 9
// 1537.692 us; speedup vs baseline: 1.7651x; 1.0860x over previous
//
#include <hip/hip_runtime.h>
#include <math.h>

// BiLSTM-CRF, round 20: r19 base (verified passing, 1670us) + two precedented
// upgrades: (1) r16's shfl-packed hout stores (kills the +32MB scalar-u16
// write amplification in the r13 lstm); (2) r17's bgemm register prefetch
// (r18 proved r17's failure was the racy r12 lstm, not this pipeline: both
// failed with identical absmax 6.0 and r18 had no bgemm change).
// B=64 S=256 V=50000 E=300 H=256 T=13
#define B_    64
#define S_    256
#define E_    300
#define H_    256
#define T_    13
#define G4_   1024   // 4*H
#define D2H_  512    // 2*H

typedef short bf16x8 __attribute__((ext_vector_type(8)));   // 8 bf16 in 4 VGPRs
typedef float f32x4  __attribute__((ext_vector_type(4)));
typedef unsigned int u32x4 __attribute__((ext_vector_type(4)));
typedef unsigned short u16;
typedef unsigned int   u32;
typedef unsigned long long u64;

#define SENT32 0x7F7F7F7Fu    // memset(0x7F) pattern; impossible packed-h dword

__device__ __forceinline__ float sigf(float x)   { return __builtin_amdgcn_rcpf(1.f + __expf(-x)); }
__device__ __forceinline__ float tanhf_(float x) { return __builtin_amdgcn_rcpf(1.f + __expf(-2.f*x))*2.f - 1.f; }

__device__ __forceinline__ u16 f2bf(float f) {
  union { float f; unsigned u; } v; v.f = f;
  unsigned r = v.u + 0x7fff + ((v.u >> 16) & 1);   // RNE
  return (u16)(r >> 16);
}
__device__ __forceinline__ float bf2f(u16 h) {
  union { unsigned u; float f; } v; v.u = ((unsigned)h) << 16;
  return v.f;
}

// coherent (agent-scope, relaxed) accessors
__device__ __forceinline__ u64 cload64(const u64* p) {
  return __hip_atomic_load(p, __ATOMIC_RELAXED, __HIP_MEMORY_SCOPE_AGENT);
}
__device__ __forceinline__ void cstore32(u32* p, u32 v) {
  __hip_atomic_store(p, v, __ATOMIC_RELAXED, __HIP_MEMORY_SCOPE_AGENT);
}

// ---------------- embedding gather -> bf16 hi/lo, K padded 300->320 ----------------
__global__ __launch_bounds__(64)
void k_embed(const int* __restrict__ x, const float* __restrict__ emb,
             u16* __restrict__ oh, u16* __restrict__ ol) {
  int bs = blockIdx.x;
  int xv = x[bs];
  const float4* src = (const float4*)(emb + (size_t)xv * E_);
  u64* dh = (u64*)(oh + (size_t)bs * 320);
  u64* dl = (u64*)(ol + (size_t)bs * 320);
  for (int q = threadIdx.x; q < 80; q += 64) {
    float4 v = (q < 75) ? src[q] : make_float4(0.f, 0.f, 0.f, 0.f);
    u16 hh[4], ll[4];
    float vv[4] = {v.x, v.y, v.z, v.w};
    #pragma unroll
    for (int j = 0; j < 4; j++) {
      hh[j] = f2bf(vv[j]);
      ll[j] = f2bf(vv[j] - bf2f(hh[j]));
    }
    dh[q] = (u64)hh[0] | ((u64)hh[1] << 16) | ((u64)hh[2] << 32) | ((u64)hh[3] << 48);
    dl[q] = (u64)ll[0] | ((u64)ll[1] << 16) | ((u64)ll[2] << 32) | ((u64)ll[3] << 48);
  }
}

// ---------------- fp32 -> bf16 hi/lo split (flat) ----------------
__global__ __launch_bounds__(256)
void k_cvtbf2(const float* __restrict__ w, u16* __restrict__ hi, u16* __restrict__ lo, int n) {
  int i = blockIdx.x * 256 + threadIdx.x;
  if (i < n) {
    float v = w[i];
    u16 h = f2bf(v);
    hi[i] = h;
    lo[i] = f2bf(v - bf2f(h));
  }
}

// ---------------- fp32 -> bf16 hi/lo, K padding, optional row permute -------------
// perm=1: source row (d, gate*256+unit) lands at buffer row (d, unit*4+gate),
// so the GEMM's output columns come out unit-major with a COALESCED epilogue.
__global__ __launch_bounds__(256)
void k_cvtpad(const float* __restrict__ w, u16* __restrict__ hi, u16* __restrict__ lo,
              int Ksrc, int Kpad, int perm) {
  int r = blockIdx.x;
  int rl = r & 1023, dd = r >> 10;
  int ro = perm ? ((dd << 10) | ((rl & 255) << 2) | (rl >> 8)) : r;
  for (int k = threadIdx.x; k < Kpad; k += 256) {
    float v = (k < Ksrc) ? w[(size_t)r * Ksrc + k] : 0.f;
    u16 h = f2bf(v);
    hi[(size_t)ro * Kpad + k] = h;
    lo[(size_t)ro * Kpad + k] = f2bf(v - bf2f(h));
  }
}

// ---------------- bias permute: (d, gate*256+unit) -> (d, unit*4+gate) ------------
__global__ __launch_bounds__(256)
void k_permb(const float* __restrict__ b, float* __restrict__ bp) {
  int i = blockIdx.x * 256 + threadIdx.x;      // 0..2047
  int rl = i & 1023, dd = i >> 10;
  bp[(dd << 10) | ((rl & 255) << 2) | (rl >> 8)] = b[i];
}

// ---------------- cond_w (512,256) -> transposed hi/lo (256,512) ----------------
__global__ __launch_bounds__(256)
void k_cvtT(const float* __restrict__ w, u16* __restrict__ hi, u16* __restrict__ lo) {
  int n = blockIdx.x;
  for (int k = threadIdx.x; k < 512; k += 256) {
    float v = w[(size_t)k * 256 + n];
    u16 h = f2bf(v);
    hi[(size_t)n * 512 + k] = h;
    lo[(size_t)n * 512 + k] = f2bf(v - bf2f(h));
  }
}

// ---------------- split-bf16 MFMA GEMM: C = A @ W^T + bias ----------------
// Register prefetch: next K-tile loaded right after barrier#2 so global
// latency hides under the 48 MFMAs. Arithmetic order unchanged.
__global__ __launch_bounds__(256)
void k_bgemm(const u16* __restrict__ Ahi, const u16* __restrict__ Alo,
             const u16* __restrict__ Whi, const u16* __restrict__ Wlo,
             const float* __restrict__ bias, float* __restrict__ C,
             int K, int N, int permute, long wStride, long bStride, long cStride)
{
  __shared__ u16 Ash[2][128 * 40];
  __shared__ u16 Wsh[2][128 * 40];

  int tid = threadIdx.x;
  int d   = blockIdx.z;
  int n0  = blockIdx.x * 128, m0 = blockIdx.y * 128;
  int lane = tid & 63;
  int w    = tid >> 6;
  int l15  = lane & 15;
  int quad = lane >> 4;
  int mh = (w >> 1) * 64, nh = (w & 1) * 64;

  int comp = tid >> 7, row = tid & 127;
  int gr = m0 + row;
  int ar = permute ? ((gr & 63) * S_ + (gr >> 6)) : gr;
  const u16* Asrc = (comp ? Alo : Ahi) + (size_t)ar * K;
  const u16* Wsrc = (comp ? Wlo : Whi) + (size_t)d * wStride + (size_t)(n0 + row) * K;
  u16* AshC = &Ash[comp][row * 40];
  u16* WshC = &Wsh[comp][row * 40];

  f32x4 acc[4][4];
  #pragma unroll
  for (int mt = 0; mt < 4; mt++)
    #pragma unroll
    for (int nt = 0; nt < 4; nt++) acc[mt][nt] = (f32x4)(0.f);

  // prologue: tile 0 into registers
  float4 a0 = *(const float4*)(Asrc);
  float4 a1 = *(const float4*)(Asrc + 8);
  float4 a2 = *(const float4*)(Asrc + 16);
  float4 a3 = *(const float4*)(Asrc + 24);
  float4 w0 = *(const float4*)(Wsrc);
  float4 w1 = *(const float4*)(Wsrc + 8);
  float4 w2 = *(const float4*)(Wsrc + 16);
  float4 w3 = *(const float4*)(Wsrc + 24);

  for (int k0 = 0; k0 < K; k0 += 32) {
    __syncthreads();               // prior frag reads done -> LDS reusable
    *(float4*)(AshC)      = a0; *(float4*)(AshC + 8)  = a1;
    *(float4*)(AshC + 16) = a2; *(float4*)(AshC + 24) = a3;
    *(float4*)(WshC)      = w0; *(float4*)(WshC + 8)  = w1;
    *(float4*)(WshC + 16) = w2; *(float4*)(WshC + 24) = w3;
    __syncthreads();

    // prefetch tile k0+32 (issued now; consumed next iteration; latency
    // overlaps the frag reads + 48 MFMAs below)
    if (k0 + 32 < K) {
      a0 = *(const float4*)(Asrc + k0 + 32);
      a1 = *(const float4*)(Asrc + k0 + 40);
      a2 = *(const float4*)(Asrc + k0 + 48);
      a3 = *(const float4*)(Asrc + k0 + 56);
      w0 = *(const float4*)(Wsrc + k0 + 32);
      w1 = *(const float4*)(Wsrc + k0 + 40);
      w2 = *(const float4*)(Wsrc + k0 + 48);
      w3 = *(const float4*)(Wsrc + k0 + 56);
    }

    bf16x8 ah[4], al[4], bh[4], bl[4];
    #pragma unroll
    for (int mt = 0; mt < 4; mt++) {
      int rr = mh + mt * 16 + l15;
      ah[mt] = *(const bf16x8*)&Ash[0][rr * 40 + quad * 8];
      al[mt] = *(const bf16x8*)&Ash[1][rr * 40 + quad * 8];
    }
    #pragma unroll
    for (int nt = 0; nt < 4; nt++) {
      int rr = nh + nt * 16 + l15;
      bh[nt] = *(const bf16x8*)&Wsh[0][rr * 40 + quad * 8];
      bl[nt] = *(const bf16x8*)&Wsh[1][rr * 40 + quad * 8];
    }
    #pragma unroll
    for (int mt = 0; mt < 4; mt++)
      #pragma unroll
      for (int nt = 0; nt < 4; nt++) {
        acc[mt][nt] = __builtin_amdgcn_mfma_f32_16x16x32_bf16(ah[mt], bh[nt], acc[mt][nt], 0, 0, 0);
        acc[mt][nt] = __builtin_amdgcn_mfma_f32_16x16x32_bf16(ah[mt], bl[nt], acc[mt][nt], 0, 0, 0);
        acc[mt][nt] = __builtin_amdgcn_mfma_f32_16x16x32_bf16(al[mt], bh[nt], acc[mt][nt], 0, 0, 0);
      }
  }

  const float* biasd = bias + (size_t)d * bStride;
  float* Cd = C + (size_t)d * cStride;
  #pragma unroll
  for (int nt = 0; nt < 4; nt++) {
    int cn = n0 + nh + nt * 16 + l15;
    float bv = biasd[cn];
    #pragma unroll
    for (int mt = 0; mt < 4; mt++) {
      int mr = m0 + mh + mt * 16 + quad * 4;
      #pragma unroll
      for (int j = 0; j < 4; j++)
        Cd[(size_t)(mr + j) * N + cn] = acc[mt][nt][j] + bv;
    }
  }
}

// ---------------- split-bf16 MFMA LSTM, 4-batch islands, in-lane cell (r13) -------
// r13 kernel (passed 5/5 in this family) with ONE change: hout stores are
// shfl-packed to 16B vectors (r16's verified block) instead of scalar u16.
// 256 WGs: blockIdx.x = d*128 + bg*8 + us. Island = (d,bg): 8 slice-WGs,
// 4 batches. A-rows: m = unit_sub*4 + gate => acc[mt][j] = gate-j pregate for
// unit us*32 + w*8 + mt*4 + quad, batch l15&3. Cell fully in-lane.
// Exchange slab per (island, step): u32[bc][unit] = hh|hl<<16; sentinel-spin.
// Slab hazard discipline: writes between spin and barrier#1; reads between
// barrier#1 and barrier#2.
__global__ __launch_bounds__(256, 1)
void k_lstm_mfma(const float* __restrict__ xg,
                 const u16* __restrict__ Whi, const u16* __restrict__ Wlo,
                 u16* __restrict__ houth, u16* __restrict__ houtl,
                 u32* __restrict__ hbx)
{
  __shared__ __align__(16) u16 hsh[4 * 256];         // 2 KB hi slab
  __shared__ __align__(16) u16 hsl[4 * 256];         // 2 KB lo slab

  int tid  = threadIdx.x;
  int us   = blockIdx.x & 7;
  int bg   = (blockIdx.x >> 3) & 15;
  int d    = blockIdx.x >> 7;
  int lane = tid & 63;
  int w    = tid >> 6;
  int l15  = lane & 15;
  int quad = lane >> 4;
  int bpc  = l15 & 3;                 // real batch column (cols 4-15 alias/discard)

  // A-frags: row = (l15&3)*256 + us*32 + w*8 + mt*4 + (l15>>2)  (gate = l15&3)
  bf16x8 afh[2][8], afl[2][8];
  {
    const u16* WbH = Whi + ((size_t)d * G4_ + (size_t)(l15 & 3) * 256
                            + us * 32 + w * 8 + (l15 >> 2)) * H_;
    const u16* WbL = Wlo + ((size_t)d * G4_ + (size_t)(l15 & 3) * 256
                            + us * 32 + w * 8 + (l15 >> 2)) * H_;
    #pragma unroll
    for (int mt = 0; mt < 2; mt++)
      #pragma unroll
      for (int kt = 0; kt < 8; kt++) {
        afh[mt][kt] = *(const bf16x8*)(WbH + (size_t)mt * 4 * H_ + kt * 32 + quad * 8);
        afl[mt][kt] = *(const bf16x8*)(WbL + (size_t)mt * 4 * H_ + kt * 32 + quad * 8);
      }
  }

  float c0 = 0.f, c1 = 0.f;
  u32 pk0 = 0, pk1 = 0;               // packed h (hi|lo<<16) from previous step

  // pull mapping: thread owns 4 slab words [pb][pu0..pu0+3]
  int pb  = tid >> 6;
  int pu0 = (tid & 63) << 2;
  bool mine = (pu0 >> 5) == us;       // own slice self-populated from registers
  int pwoff = ((pb * 256 + pu0) * 2) ^ ((pb & 1) << 6);   // LDS byte, 8B-aligned

  // cell/self-pop constants: units u0c (mt=0), u0c+4 (mt=1), batch bpc
  int u0c   = us * 32 + w * 8 + quad;
  int soff0 = ((bpc * 256 + u0c) * 2)     ^ ((bpc & 1) << 6);
  int soff1 = ((bpc * 256 + u0c + 4) * 2) ^ ((bpc & 1) << 6);

  const float* xgd = xg + (size_t)d * S_ * B_ * G4_;
  u32* hb = hbx + (size_t)(d * 16 + bg) * S_ * 1024;

  for (int it = 0; it < S_; it++) {
    int s = d ? (S_ - 1 - it) : it;

    // acc init from unit-major xg (issued early; latency hides under the poll)
    f32x4 accA[2], accB[2];
    const float* xgrow = xgd + ((size_t)s * B_ + (bg * 4 + bpc)) * G4_
                       + (size_t)(us * 32 + w * 8 + quad) * 4;
    accA[0] = *(const f32x4*)(xgrow);
    accA[1] = *(const f32x4*)(xgrow + 16);
    accB[0] = (f32x4)(0.f);
    accB[1] = (f32x4)(0.f);

    if (it > 0) {
      // phase 2a: remote pull (spin on the data words themselves)
      if (!mine) {
        const u64* src = (const u64*)(hb + (size_t)(it - 1) * 1024 + pb * 256 + pu0);
        u64 a = cload64(src), b2 = cload64(src + 1);
        while (((u32)a == SENT32) | ((u32)(a >> 32) == SENT32) |
               ((u32)b2 == SENT32) | ((u32)(b2 >> 32) == SENT32)) {
          __builtin_amdgcn_s_sleep(1);
          a = cload64(src); b2 = cload64(src + 1);
        }
        u64 hi64 = (a & 0xFFFFull) | (((a >> 32) & 0xFFFFull) << 16)
                 | ((b2 & 0xFFFFull) << 32) | (((b2 >> 32) & 0xFFFFull) << 48);
        u64 lo64 = ((a >> 16) & 0xFFFFull) | (((a >> 48) & 0xFFFFull) << 16)
                 | (((b2 >> 16) & 0xFFFFull) << 32) | ((b2 >> 48) << 48);
        *(u64*)((char*)hsh + pwoff) = hi64;
        *(u64*)((char*)hsl + pwoff) = lo64;
      }
      // phase 2b: self-populate own slice from previous step's registers
      if (l15 < 4) {
        *(u16*)((char*)hsh + soff0) = (u16)pk0;
        *(u16*)((char*)hsl + soff0) = (u16)(pk0 >> 16);
        *(u16*)((char*)hsh + soff1) = (u16)pk1;
        *(u16*)((char*)hsl + soff1) = (u16)(pk1 >> 16);
      }
      __syncthreads();   // barrier#1: slab(it-1) complete

      #pragma unroll
      for (int kt = 0; kt < 8; kt++) {
        int coff = ((bpc * 256 + (kt * 4 + quad) * 8) * 2) ^ ((bpc & 1) << 6);
        bf16x8 bh = *(const bf16x8*)((const char*)hsh + coff);
        bf16x8 bl = *(const bf16x8*)((const char*)hsl + coff);
        #pragma unroll
        for (int mt = 0; mt < 2; mt++) {
          accA[mt] = __builtin_amdgcn_mfma_f32_16x16x32_bf16(afh[mt][kt], bh, accA[mt], 0, 0, 0);
          accB[mt] = __builtin_amdgcn_mfma_f32_16x16x32_bf16(afh[mt][kt], bl, accB[mt], 0, 0, 0);
          accB[mt] = __builtin_amdgcn_mfma_f32_16x16x32_bf16(afl[mt][kt], bh, accB[mt], 0, 0, 0);
        }
      }
    }

    // in-lane cell update: acc[mt][j] = gate j (i,f,g,o) of unit u0c + mt*4
    u32* hbrow = hb + (size_t)it * 1024 + bpc * 256 + u0c;
    {
      f32x4 g0 = accA[0] + accB[0];
      c0 = sigf(g0[1]) * c0 + sigf(g0[0]) * tanhf_(g0[2]);
      float h0 = sigf(g0[3]) * tanhf_(c0);
      u16 hh = f2bf(h0), hl = f2bf(h0 - bf2f(hh));
      pk0 = (u32)hh | ((u32)hl << 16);
      if (l15 < 4) cstore32(hbrow, pk0);           // exchange ASAP
    }
    {
      f32x4 g1 = accA[1] + accB[1];
      c1 = sigf(g1[1]) * c1 + sigf(g1[0]) * tanhf_(g1[2]);
      float h1 = sigf(g1[3]) * tanhf_(c1);
      u16 hh = f2bf(h1), hl = f2bf(h1 - bf2f(hh));
      pk1 = (u32)hh | ((u32)hl << 16);
      if (l15 < 4) cstore32(hbrow + 4, pk1);
    }

    // layer output: shfl-pack 8 consecutive units -> 2 x 16B stores (r16 block)
    {
      u32 x1_0 = __shfl(pk0, l15 + 16), x1_1 = __shfl(pk1, l15 + 16);
      u32 x2_0 = __shfl(pk0, l15 + 32), x2_1 = __shfl(pk1, l15 + 32);
      u32 x3_0 = __shfl(pk0, l15 + 48), x3_1 = __shfl(pk1, l15 + 48);
      if (lane < 4) {
        u32x4 hivec, lovec;
        hivec[0] = (pk0 & 0xFFFFu)  | ((x1_0 & 0xFFFFu) << 16);
        hivec[1] = (x2_0 & 0xFFFFu) | ((x3_0 & 0xFFFFu) << 16);
        hivec[2] = (pk1 & 0xFFFFu)  | ((x1_1 & 0xFFFFu) << 16);
        hivec[3] = (x2_1 & 0xFFFFu) | ((x3_1 & 0xFFFFu) << 16);
        lovec[0] = (pk0 >> 16)  | (x1_0 & 0xFFFF0000u);
        lovec[1] = (x2_0 >> 16) | (x3_0 & 0xFFFF0000u);
        lovec[2] = (pk1 >> 16)  | (x1_1 & 0xFFFF0000u);
        lovec[3] = (x2_1 >> 16) | (x3_1 & 0xFFFF0000u);
        size_t ho = ((size_t)(bg * 4 + lane) * S_ + s) * D2H_ + d * H_ + us * 32 + w * 8;
        *(u32x4*)(houth + ho) = hivec;
        *(u32x4*)(houtl + ho) = lovec;
      }
    }

    __syncthreads();   // barrier#2: drain slab reads before next iter's writes
  }
}

// ---------------- block reduction helpers ----------------
__device__ __forceinline__ float bsum(float v, float* sb) {
  int t = threadIdx.x;
  sb[t] = v; __syncthreads();
  for (int s = 128; s; s >>= 1) { if (t < s) sb[t] += sb[t + s]; __syncthreads(); }
  float r = sb[0]; __syncthreads(); return r;
}
__device__ __forceinline__ float bmax(float v, float* sb) {
  int t = threadIdx.x;
  sb[t] = v; __syncthreads();
  for (int s = 128; s; s >>= 1) { if (t < s) sb[t] = fmaxf(sb[t], sb[t + s]); __syncthreads(); }
  float r = sb[0]; __syncthreads(); return r;
}

// ---------------- pos branch ----------------
__global__ __launch_bounds__(256)
void k_pos(const float* __restrict__ pos, const float* __restrict__ fc1w, const float* __restrict__ fc1b,
           const float* __restrict__ fc2w, const float* __restrict__ fc2b,
           const float* __restrict__ lng, const float* __restrict__ lnb, float* __restrict__ pos_out)
{
  __shared__ float sp[256], sh[256], sb[256];
  int b = blockIdx.x, t = threadIdx.x;
  sp[t] = pos[b * 256 + t];
  __syncthreads();
  float a1 = fc1b[t];
  for (int s = 0; s < 256; s++) a1 += sp[s] * fc1w[s * 256 + t];
  a1 = fmaxf(a1, 0.f);
  sh[t] = a1; __syncthreads();
  float a2 = fc2b[t] + sp[t];
  for (int s = 0; s < 256; s++) a2 += sh[s] * fc2w[s * 256 + t];
  float m   = bsum(a2, sb) * (1.f / 256.f);
  float cen = a2 - m;
  float var = bsum(cen * cen, sb) * (1.f / 256.f);
  pos_out[b * 256 + t] = cen * rsqrtf(var + 1e-5f) * lng[t] + lnb[t];
}

// ---------------- CLN stage A ----------------
__global__ __launch_bounds__(256)
void k_clnA(const float* __restrict__ pos_out, const float* __restrict__ wd, const float* __restrict__ bd,
            const float* __restrict__ cw, const float* __restrict__ cb,
            float* __restrict__ wvec, float* __restrict__ bbvec)
{
  __shared__ float sp[256];
  int b = blockIdx.x, t = threadIdx.x;
  sp[t] = pos_out[b * 256 + t];
  __syncthreads();
  const float4* wdr = (const float4*)(wd + (size_t)t * 256);
  const float4* bdr = (const float4*)(bd + (size_t)t * 256);
  float aw = 0.f, ab = 0.f;
  for (int q = 0; q < 64; q++) {
    float4 w4 = wdr[q], b4 = bdr[q];
    float s0 = sp[q*4], s1 = sp[q*4+1], s2 = sp[q*4+2], s3 = sp[q*4+3];
    aw += s0*w4.x + s1*w4.y + s2*w4.z + s3*w4.w;
    ab += s0*b4.x + s1*b4.y + s2*b4.z + s3*b4.w;
  }
  wvec [b * 256 + t] = aw + cw[t];
  bbvec[b * 256 + t] = ab + cb[t];
}

// ---------------- CLN stage B + sentence dot ----------------
__global__ __launch_bounds__(256)
void k_clnB(const float* __restrict__ oc, const float* __restrict__ wvec, const float* __restrict__ bbvec,
            const float* __restrict__ alw, const float* __restrict__ alb,
            float* __restrict__ outn, float* __restrict__ sentence)
{
  __shared__ float sb[256];
  int bs = blockIdx.x, t = threadIdx.x;
  int b = bs >> 8;
  float v   = oc[(size_t)bs * 256 + t];
  float m   = bsum(v, sb) * (1.f / 256.f);
  float cen = v - m;
  float var = bsum(cen * cen, sb) * (1.f / 256.f);
  float o   = cen * rsqrtf(var + 1e-12f) * wvec[b * 256 + t] + bbvec[b * 256 + t];
  outn[(size_t)bs * 256 + t] = o;
  float sv = bsum(o * alw[t], sb);
  if (t == 0) sentence[bs] = sv + alb[0];
}

// ---------------- attention ----------------
__global__ __launch_bounds__(256)
void k_att(const float* __restrict__ sentence,
           const float* __restrict__ wq, const float* __restrict__ bq,
           const float* __restrict__ wk, const float* __restrict__ bk,
           const float* __restrict__ wv, const float* __restrict__ bv,
           const float* __restrict__ lng, const float* __restrict__ lnb,
           float* __restrict__ att)
{
  __shared__ float ss[256], sb[256];
  int b = blockIdx.x, t = threadIdx.x;
  ss[t] = sentence[b * 256 + t];
  __syncthreads();
  float q = bq[t], k = bk[t], vv = bv[t];
  for (int s = 0; s < 256; s++) {
    float sv = ss[s];
    q  += sv * wq[s * 256 + t];
    k  += sv * wk[s * 256 + t];
    vv += sv * wv[s * 256 + t];
  }
  float x  = q * k * (1.f / 16.f);
  float mx = bmax(x, sb);
  float e  = expf(x - mx);
  float sm = bsum(e, sb);
  float a  = (e / sm) * vv;
  float m   = bsum(a, sb) * (1.f / 256.f);
  float cen = a - m;
  float var = bsum(cen * cen, sb) * (1.f / 256.f);
  att[b * 256 + t] = cen * rsqrtf(var + 1e-5f) * lng[t] + lnb[t];
}

// ---------------- logits ----------------
__global__ __launch_bounds__(64)
void k_out(const float* __restrict__ outn, const float* __restrict__ att,
           const float* __restrict__ ow, const float* __restrict__ ob,
           float* __restrict__ logits)
{
  __shared__ float row[256];
  int bs = blockIdx.x, t = threadIdx.x;
  ((float4*)row)[t] = ((const float4*)(outn + (size_t)bs * 256))[t];
  __syncthreads();
  float a = att[bs];
  if (t < T_) {
    float acc = 0.f;
    for (int c = 0; c < 256; c++) acc += row[c] * ow[c * T_ + t];
    logits[(size_t)bs * T_ + t] = a * acc + ob[t];
  }
}

// ---------------- Viterbi ----------------
__global__ __launch_bounds__(64)
void k_viterbi(const float* __restrict__ logits, const float* __restrict__ start,
               const float* __restrict__ endv, const float* __restrict__ trans,
               float* __restrict__ tags)
{
  __shared__ float sc[16];
  __shared__ float str[169];
  __shared__ unsigned char hist[255 * 13];
  __shared__ int tg[256];
  int b = blockIdx.x, t = threadIdx.x;
  for (int i = t; i < 169; i += 64) str[i] = trans[i];
  if (t < 13) sc[t] = start[t] + logits[((size_t)b * 256) * 13 + t];
  __syncthreads();
  for (int s = 1; s < 256; s++) {
    float best = -1e30f; int bi = 0;
    if (t < 13) {
      best = sc[0] + str[t]; bi = 0;
      for (int i = 1; i < 13; i++) {
        float v = sc[i] + str[i * 13 + t];
        if (v > best) { best = v; bi = i; }
      }
    }
    __syncthreads();
    if (t < 13) {
      sc[t] = best + logits[((size_t)b * 256 + s) * 13 + t];
      hist[(s - 1) * 13 + t] = (unsigned char)bi;
    }
    __syncthreads();
  }
  if (t == 0) {
    float best = sc[0] + endv[0]; int last = 0;
    for (int j = 1; j < 13; j++) {
      float v = sc[j] + endv[j];
      if (v > best) { best = v; last = j; }
    }
    tg[255] = last;
    int cur = last;
    for (int s = 254; s >= 0; s--) { cur = hist[s * 13 + cur]; tg[s] = cur; }
  }
  __syncthreads();
  for (int s = t; s < 256; s += 64) tags[b * 256 + s] = (float)tg[s];
}

// ---------------- launch ----------------
extern "C" void kernel_launch(void* const* d_in, const int* in_sizes, int n_in,
                              void* d_out, int out_size, void* d_ws, size_t ws_size,
                              hipStream_t stream)
{
  const int*   x     = (const int*)  d_in[0];
  const float* pos   = (const float*)d_in[1];
  const float* emb   = (const float*)d_in[2];
  const float* Wih0  = (const float*)d_in[3];
  const float* Whh0  = (const float*)d_in[4];
  const float* b0    = (const float*)d_in[5];
  const float* Wih1  = (const float*)d_in[6];
  const float* Whh1  = (const float*)d_in[7];
  const float* b1    = (const float*)d_in[8];
  const float* fc1w  = (const float*)d_in[9];
  const float* fc1b  = (const float*)d_in[10];
  const float* fc2w  = (const float*)d_in[11];
  const float* fc2b  = (const float*)d_in[12];
  const float* plng  = (const float*)d_in[13];
  const float* plnb  = (const float*)d_in[14];
  const float* condw = (const float*)d_in[15];
  const float* condb = (const float*)d_in[16];
  const float* clnw  = (const float*)d_in[17];
  const float* clnb  = (const float*)d_in[18];
  const float* clnwd = (const float*)d_in[19];
  const float* clnbd = (const float*)d_in[20];
  const float* wq    = (const float*)d_in[21];
  const float* bq    = (const float*)d_in[22];
  const float* wk    = (const float*)d_in[23];
  const float* bk    = (const float*)d_in[24];
  const float* wv    = (const float*)d_in[25];
  const float* bv    = (const float*)d_in[26];
  const float* atlng = (const float*)d_in[27];
  const float* atlnb = (const float*)d_in[28];
  const float* alw   = (const float*)d_in[29];
  const float* alb   = (const float*)d_in[30];
  const float* ow    = (const float*)d_in[31];
  const float* ob    = (const float*)d_in[32];
  const float* cstart= (const float*)d_in[33];
  const float* cend  = (const float*)d_in[34];
  const float* ctrans= (const float*)d_in[35];

  const size_t BS = (size_t)B_ * S_;   // 16384
  float* ws = (float*)d_ws;
  float* r1   = ws;                    // embA hi/lo -> out_cond
  float* xg   = r1 + 5242880;          // fp32 pre-gates [2][S][B][unit*4+gate]
  float* l0r  = xg + 33554432;         // l0 hi/lo -> lstm1 exchange -> outn
  float* l1r  = l0r + 8388608;         // lstm0 exchange -> l1 hi/lo
  float* pos_out  = l1r + 8388608;
  float* wvec     = pos_out + 16384;
  float* bbvec    = wvec + 16384;
  float* sentence = bbvec + 16384;
  float* attv     = sentence + 16384;
  unsigned* flags = (unsigned*)(attv + 16384);     // (unused; layout kept)
  u16* whhh0 = (u16*)(flags + 65536);              // Whh splits: 4 x 524288 u16
  u16* whhl0 = whhh0 + 524288;
  u16* whhh1 = whhl0 + 524288;
  u16* whhl1 = whhh1 + 524288;
  u16* wih0h = whhl1 + 524288;                     // [2][1024][320] (row-permuted)
  u16* wih0l = wih0h + 655360;
  u16* wih1h = wih0l + 655360;                     // [2][1024][512] (row-permuted)
  u16* wih1l = wih1h + 1048576;
  u16* condTh = wih1l + 1048576;                   // [256][512]
  u16* condTl = condTh + 131072;
  float* b0p  = (float*)(condTl + 131072);         // permuted biases [2][1024]
  float* b1p  = b0p + 2048;

  u16* embh = (u16*)r1;
  u16* embl = embh + 5242880;
  float* out_cond = r1;
  u16* l0h = (u16*)l0r;
  u16* l0l = l0h + 8388608;
  u16* l1h = (u16*)l1r;
  u16* l1l = l1h + 8388608;
  u32* hb0 = (u32*)l1r;                 // lstm0 exchange (l1r free until lstm1 hout)
  u32* hb1 = (u32*)l0r;                 // lstm1 exchange (l0 consumed by bgemm1)
  const size_t HBBYTES = (size_t)32 * S_ * 1024 * sizeof(u32);  // 33,554,432 B
  float* outn = l0r;
  float* logits = (float*)d_out;
  float* tags   = logits + BS * T_;

  // sentinel-fill lstm0 exchange region (l1r untouched until lstm0)
  hipMemsetAsync(hb0, 0x7F, HBBYTES, stream);

  k_embed <<<dim3(B_ * S_), dim3(64), 0, stream>>>(x, emb, embh, embl);
  k_cvtbf2<<<dim3(2048), dim3(256), 0, stream>>>(Whh0, whhh0, whhl0, 2 * G4_ * H_);
  k_cvtbf2<<<dim3(2048), dim3(256), 0, stream>>>(Whh1, whhh1, whhl1, 2 * G4_ * H_);
  k_cvtpad<<<dim3(2048), dim3(256), 0, stream>>>(Wih0, wih0h, wih0l, 300, 320, 1);
  k_cvtpad<<<dim3(2048), dim3(256), 0, stream>>>(Wih1, wih1h, wih1l, 512, 512, 1);
  k_permb <<<dim3(8),    dim3(256), 0, stream>>>(b0, b0p);
  k_permb <<<dim3(8),    dim3(256), 0, stream>>>(b1, b1p);
  k_cvtT  <<<dim3(256),  dim3(256), 0, stream>>>(condw, condTh, condTl);

  // layer-0 pre-gates (unit-major via permuted W rows; coalesced epilogue)
  k_bgemm<<<dim3(8, 128, 2), dim3(256), 0, stream>>>(
      embh, embl, wih0h, wih0l, b0p, xg, 320, G4_, 1,
      (long)G4_ * 320, (long)G4_, (long)BS * G4_);
  k_lstm_mfma<<<dim3(256), dim3(256), 0, stream>>>(
      xg, whhh0, whhl0, l0h, l0l, hb0);

  // layer-1 pre-gates
  k_bgemm<<<dim3(8, 128, 2), dim3(256), 0, stream>>>(
      l0h, l0l, wih1h, wih1l, b1p, xg, 512, G4_, 1,
      (long)G4_ * 512, (long)G4_, (long)BS * G4_);
  // sentinel-fill lstm1 exchange region (l0h just consumed by the bgemm above)
  hipMemsetAsync(hb1, 0x7F, HBBYTES, stream);
  k_lstm_mfma<<<dim3(256), dim3(256), 0, stream>>>(
      xg, whhh1, whhl1, l1h, l1l, hb1);

  // cond projection (permute=0: no remap anywhere)
  k_bgemm<<<dim3(2, 128, 1), dim3(256), 0, stream>>>(
      l1h, l1l, condTh, condTl, condb, out_cond, 512, 256, 0, 0, 0, 0);

  k_pos <<<dim3(B_), dim3(256), 0, stream>>>(pos, fc1w, fc1b, fc2w, fc2b, plng, plnb, pos_out);
  k_clnA<<<dim3(B_), dim3(256), 0, stream>>>(pos_out, clnwd, clnbd, clnw, clnb, wvec, bbvec);
  k_clnB<<<dim3(B_ * S_), dim3(256), 0, stream>>>(out_cond, wvec, bbvec, alw, alb, outn, sentence);
  k_att <<<dim3(B_), dim3(256), 0, stream>>>(sentence, wq, bq, wk, bk, wv, bv, atlng, atlnb, attv);
  k_out <<<dim3(B_ * S_), dim3(64), 0, stream>>>(outn, attv, ow, ob, logits);
  k_viterbi<<<dim3(B_), dim3(64), 0, stream>>>(logits, cstart, cend, ctrans, tags);
}